// Round 6
// baseline (5434.890 us; speedup 1.0000x reference)
//
#include <hip/hip_runtime.h>
#include <cstddef>

#define T_  128
#define B_  64
#define F_  75
#define H_  512
#define G4_ 2048
#define TB_ (T_ * B_)
#define KP_ 128   // padded K for F=75 inputs

typedef __bf16 bf16x8 __attribute__((ext_vector_type(8)));
typedef float  f32x4  __attribute__((ext_vector_type(4)));
typedef unsigned long long u64;
typedef unsigned long long __attribute__((may_alias)) u64a;

__device__ __forceinline__ short f2b(float x) {
    union { float f; unsigned u; } v; v.f = x;
    return (short)((v.u + 0x7fffu + ((v.u >> 16) & 1u)) >> 16);
}
__device__ __forceinline__ float b2f(short s) {
    union { float f; unsigned u; } v; v.u = ((unsigned)(unsigned short)s) << 16;
    return v.f;
}
__device__ __forceinline__ void gload16(const void* g, void* l) {
    __builtin_amdgcn_global_load_lds(
        (const __attribute__((address_space(1))) void*)g,
        (__attribute__((address_space(3))) void*)l, 16, 0, 0);
}
__device__ __forceinline__ float fsig(float x) {
    return __builtin_amdgcn_rcpf(1.f + __expf(-x));
}
__device__ __forceinline__ float ftanh(float x) {
    return 1.f - 2.f * __builtin_amdgcn_rcpf(1.f + __expf(2.f * x));
}

// ---------------------------------------------------------------------------
// bf16 MFMA GEMM. If P != null: write fp32 results into the step-kernel's
// packed XW layout  P[t][ub(32)][r(4)][tidS(256)][g(4)]  (biases included).
// Else: C(M,N) fp32 row-major.
// ---------------------------------------------------------------------------
__global__ __launch_bounds__(256) void gemm_bf16(
    const short* __restrict__ A, const short* __restrict__ Bm,
    float* __restrict__ C, float* __restrict__ P, int M, int N, int K,
    const float* __restrict__ bias1, const float* __restrict__ bias2)
{
    __shared__ short As[4096];
    __shared__ short Bs[4096];
    const int tid = threadIdx.x;
    const int m_base = blockIdx.y * 128;
    const int n_base = blockIdx.x * 128;
    const int w = tid >> 6, lane = tid & 63;
    const int wm = (w >> 1) * 64, wn = (w & 1) * 64;
    const int lm = lane & 15, q = lane >> 4;

    f32x4 acc[4][4];
#pragma unroll
    for (int i = 0; i < 4; i++)
#pragma unroll
        for (int j = 0; j < 4; j++)
#pragma unroll
            for (int r = 0; r < 4; r++) acc[i][j][r] = 0.f;

    const int s0 = tid, s1 = tid + 256;
    const int r0 = s0 & 127, c0 = s0 >> 7;
    const int r1 = s1 & 127, c1 = s1 >> 7;

    for (int k0 = 0; k0 < K; k0 += 32) {
        __syncthreads();
        gload16(A + (size_t)(m_base + r0) * K + k0 + c0 * 8, &As[s0 * 8]);
        gload16(A + (size_t)(m_base + r1) * K + k0 + c1 * 8, &As[s1 * 8]);
        gload16(Bm + (size_t)(n_base + r0) * K + k0 + c0 * 8, &Bs[s0 * 8]);
        gload16(Bm + (size_t)(n_base + r1) * K + k0 + c1 * 8, &Bs[s1 * 8]);
        __syncthreads();
        bf16x8 af[4], bfv[4];
#pragma unroll
        for (int i = 0; i < 4; i++) {
            af[i]  = *(const bf16x8*)&As[((q * 128) + wm + i * 16 + lm) * 8];
            bfv[i] = *(const bf16x8*)&Bs[((q * 128) + wn + i * 16 + lm) * 8];
        }
#pragma unroll
        for (int i = 0; i < 4; i++)
#pragma unroll
            for (int j = 0; j < 4; j++)
                acc[i][j] = __builtin_amdgcn_mfma_f32_16x16x32_bf16(
                    af[i], bfv[j], acc[i][j], 0, 0, 0);
    }

#pragma unroll
    for (int i = 0; i < 4; i++) {
#pragma unroll
        for (int j = 0; j < 4; j++) {
            const int gm0 = m_base + wm + i * 16 + q * 4;
            const int gn = n_base + wn + j * 16 + lm;
            float bb = (bias1 ? bias1[gn] : 0.f) + (bias2 ? bias2[gn] : 0.f);
            if (P) {
                const int g = gn >> 9, u = gn & 511;
                const int ub = u >> 4, lmu = u & 15;
#pragma unroll
                for (int r = 0; r < 4; r++) {
                    const int gm = gm0 + r;
                    const int t = gm >> 6, b = gm & 63;
                    const int tidS = (b >> 4) * 64 + ((b >> 2) & 3) * 16 + lmu;
                    size_t idx = ((((size_t)t * 32 + ub) * 4 + (b & 3)) * 256 + tidS) * 4 + g;
                    P[idx] = acc[i][j][r] + bb;
                }
            } else {
#pragma unroll
                for (int r = 0; r < 4; r++)
                    C[(size_t)(gm0 + r) * N + gn] = acc[i][j][r] + bb;
            }
        }
    }
}

// ---------------------------------------------------------------------------
// Pack Whh (2,4H,H) fp32 -> bf16 B-fragments:
// Wpk[dir][ub(32)][g(4)][it(16)][lane(64)][8]
// ---------------------------------------------------------------------------
__global__ __launch_bounds__(256) void pack_whh(
    const float* __restrict__ W, short* __restrict__ Wpk)
{
    int i = blockIdx.x * 256 + threadIdx.x;
    if (i >= 2 * G4_ * H_) return;
    int e = i & 7, lane = (i >> 3) & 63, it = (i >> 9) & 15;
    int g = (i >> 13) & 3, ub = (i >> 15) & 31, dir = (i >> 20) & 1;
    int lm = lane & 15, qq = lane >> 4;
    float v = W[((size_t)dir * G4_ + g * H_ + ub * 16 + lm) * H_
                + it * 32 + qq * 8 + e];
    Wpk[i] = f2b(v);
}

// ---------------------------------------------------------------------------
// bar layout (u32): [0..63] per-BLOCK step tags (dir*32 + ub), counting +4
// per step (one RMW per wave). One 128B line per dir. Zeroed only at phase 0
// (monotonic across phases: after phase p, every tag == 4*p*T_).
// ---------------------------------------------------------------------------
__global__ __launch_bounds__(256) void init_phase(
    const float* __restrict__ h0s, short* __restrict__ Ht,
    unsigned* __restrict__ bar, int zero_bar)
{
    int i = blockIdx.x * 256 + threadIdx.x;
    if (i < 2 * B_ * H_) Ht[i] = f2b(h0s[i]);
    if (zero_bar && i < 64) bar[i] = 0;
}

__global__ __launch_bounds__(256) void ht_to_f32(
    const short* __restrict__ Ht0, float* __restrict__ out)
{
    int i = blockIdx.x * 256 + threadIdx.x;
    if (i < 2 * B_ * H_) out[i] = b2f(Ht0[i]);
}

// ---------------------------------------------------------------------------
// Persistent phase kernel. grid (32, 2): block = 16 units, 1 dir.
// Whh in 64KB LDS (B-frag order). All cross-block traffic agent-scope.
// ZERO barriers in the step loop; per-WAVE decoupling throughout:
//  - arrive: each wave publishes its own 16 batch rows, drains its OWN
//    vmcnt, then lane0 does ONE atomicAdd(+1) on the block tag (counts to
//    4 per step). A wave's arrival is never gated on sibling waves.
//  - detect: tight 32-lane check-first poll of the dir's single tag line:
//    all tags >= 4*(global step). Gather cannot start early because the
//    poll dominates it (tags>=4s+4 implies all waves of all blocks
//    published step s, which implies all gathers of step s completed ->
//    2-buffer overwrite is safe).
//  - Tb transpose tile is wave-private on write AND read (may_alias u64
//    read; compiler fences pin LDS/atomic order -- R2's NaN lesson).
// ---------------------------------------------------------------------------
__global__ __launch_bounds__(256, 1) void lstm_phase(
    const float* __restrict__ XW,   // packed (2,T,32,4,256,4) fp32
    const short* __restrict__ Wpk,  // packed Whh bf16
    short* __restrict__ Ht,         // (2buf,2dir,64b,512u) bf16
    const float* __restrict__ c0p,  // (2,B,H) fp32 initial c
    short* __restrict__ Y,          // (T,B,2H) bf16 or null
    unsigned* __restrict__ bar, int phase)
{
    __shared__ short Ws[32768];     // 64 KB packed weights
    __shared__ short Tb[64 * 24];   // transpose buffer (48B row stride)
    const int dir = blockIdx.y, ub = blockIdx.x, u0 = ub * 16;
    const int tid = threadIdx.x, w = tid >> 6, lane = tid & 63;
    const int lm = lane & 15, q = lane >> 4;

    const short* wsrc = Wpk + (size_t)(dir * 32 + ub) * 32768;
#pragma unroll
    for (int p = 0; p < 16; p++)
        gload16(wsrc + (tid + 256 * p) * 8, &Ws[(tid + 256 * p) * 8]);

    const int b0 = w * 16 + q * 4;   // this lane's 4 batch rows
    const int u = u0 + lm;           // this lane's hidden unit
    unsigned* slots = bar + dir * 32;

    float c[4];
    f32x4 xw[4];                     // [r] -> 4 gates
#pragma unroll
    for (int r = 0; r < 4; r++)
        c[r] = c0p[(size_t)dir * B_ * H_ + (size_t)(b0 + r) * H_ + u];
    {
        const int t0 = dir ? (T_ - 1) : 0;
        const float* xp = XW + ((size_t)dir * T_ + t0) * (B_ * G4_) + (size_t)ub * 4096;
#pragma unroll
        for (int r = 0; r < 4; r++)
            xw[r] = *(const f32x4*)(xp + r * 1024 + tid * 4);
    }
    __syncthreads();   // Ws resident (only barrier in the kernel)

    const unsigned base4 = 4u * (unsigned)(phase * T_);

    for (int s = 0; s < T_; s++) {
        const int t = dir ? (T_ - 1 - s) : s;
        const short* Hc = Ht + ((size_t)((s & 1) * 2 + dir) << 15);

        // ---- detect: all blocks (all waves) published step s-1
        {
            const unsigned tgt4 = base4 + 4u * (unsigned)s;
            unsigned v;
            for (;;) {
                v = (lane < 32)
                    ? __hip_atomic_load(&slots[lane], __ATOMIC_RELAXED, __HIP_MEMORY_SCOPE_AGENT)
                    : tgt4;
                if (__all(v >= tgt4)) break;
                __builtin_amdgcn_s_sleep(1);
            }
        }
        __asm__ volatile("" ::: "memory");   // no gather motion above poll

        // ---- h A-fragments (full h vector), agent-scope bulk gather
        u64 hq[32];
        const short* hrow = Hc + (w * 16 + lm) * 512 + q * 8;
#pragma unroll
        for (int it = 0; it < 16; it++) {
            const u64* hp = (const u64*)(hrow + it * 32);
            hq[2 * it]     = __hip_atomic_load((u64*)hp,     __ATOMIC_RELAXED, __HIP_MEMORY_SCOPE_AGENT);
            hq[2 * it + 1] = __hip_atomic_load((u64*)hp + 1, __ATOMIC_RELAXED, __HIP_MEMORY_SCOPE_AGENT);
        }

        f32x4 acc[4];
#pragma unroll
        for (int g = 0; g < 4; g++)
#pragma unroll
            for (int r = 0; r < 4; r++) acc[g][r] = 0.f;

#pragma unroll
        for (int it = 0; it < 16; it++) {
            union { u64 q2[2]; bf16x8 v; } ua;
            ua.q2[0] = hq[2 * it]; ua.q2[1] = hq[2 * it + 1];
#pragma unroll
            for (int g = 0; g < 4; g++) {
                bf16x8 bv = *(const bf16x8*)&Ws[((g * 16 + it) * 64 + lane) * 8];
                acc[g] = __builtin_amdgcn_mfma_f32_16x16x32_bf16(ua.v, bv, acc[g], 0, 0, 0);
            }
        }

        // ---- pointwise gates; h -> LDS transpose tile (wave-private rows)
#pragma unroll
        for (int r = 0; r < 4; r++) {
            float gi = acc[0][r] + xw[r][0];
            float gf = acc[1][r] + xw[r][1];
            float gg = acc[2][r] + xw[r][2];
            float go = acc[3][r] + xw[r][3];
            float cc = fsig(gf) * c[r] + fsig(gi) * ftanh(gg);
            c[r] = cc;
            Tb[(b0 + r) * 24 + lm] = f2b(fsig(go) * ftanh(cc));
        }
        __asm__ volatile("" ::: "memory");   // order Tb writes before Tb read

        // ---- per-wave publish (u64 per thread), own drain, own arrive
        const int b = tid >> 2, qd = tid & 3;      // b in [16w, 16w+16)
        u64 v0 = *(const u64a*)&Tb[b * 24 + qd * 4];
        {
            short* Hn = Ht + ((size_t)(((s + 1) & 1) * 2 + dir) << 15);
            __hip_atomic_store((u64*)(Hn + b * 512 + u0 + qd * 4), v0,
                               __ATOMIC_RELAXED, __HIP_MEMORY_SCOPE_AGENT);
        }
        __asm__ volatile("s_waitcnt vmcnt(0)" ::: "memory");
        if (lane == 0)
            __hip_atomic_fetch_add(&slots[ub], 1u,
                                   __ATOMIC_RELAXED, __HIP_MEMORY_SCOPE_AGENT);

        // ---- Y store + next-step XW prefetch (overlap next poll window)
        if (Y)
            *(u64a*)(Y + ((size_t)t * B_ + b) * (2 * H_) + dir * H_ + u0 + qd * 4) = v0;
        if (s < T_ - 1) {
            const int tn = dir ? (T_ - 2 - s) : (s + 1);
            const float* xp = XW + ((size_t)dir * T_ + tn) * (B_ * G4_) + (size_t)ub * 4096;
#pragma unroll
            for (int r = 0; r < 4; r++)
                xw[r] = *(const f32x4*)(xp + r * 1024 + tid * 4);
        }
    }
}

// ---------------------------------------------------------------------------
// fp32 GEMM for tiny attention matmuls (bounds-checked), act 0/1/2
// ---------------------------------------------------------------------------
__global__ __launch_bounds__(256) void gemm_bt(
    const float* __restrict__ A, const float* __restrict__ Bm,
    float* __restrict__ C, int M, int N, int K,
    const float* __restrict__ bias1, int act)
{
    __shared__ float As[16][68];
    __shared__ float Bs[16][68];
    const int tid = threadIdx.x;
    const int m_base = blockIdx.y * 64;
    const int n_base = blockIdx.x * 64;
    const int tm = tid >> 4, tn = tid & 15;
    float acc[4][4] = {};

    for (int k0 = 0; k0 < K; k0 += 16) {
#pragma unroll
        for (int i = 0; i < 4; i++) {
            int idx = tid * 4 + i;
            int r = idx >> 4, kk = idx & 15;
            int gm = m_base + r, gk = k0 + kk;
            As[kk][r] = (gm < M && gk < K) ? A[(size_t)gm * K + gk] : 0.f;
            int gn = n_base + r;
            Bs[kk][r] = (gn < N && gk < K) ? Bm[(size_t)gn * K + gk] : 0.f;
        }
        __syncthreads();
#pragma unroll
        for (int kk = 0; kk < 16; kk++) {
            float4 av = *(const float4*)&As[kk][tm * 4];
            float4 bv = *(const float4*)&Bs[kk][tn * 4];
            float a[4] = {av.x, av.y, av.z, av.w};
            float b[4] = {bv.x, bv.y, bv.z, bv.w};
#pragma unroll
            for (int i = 0; i < 4; i++)
#pragma unroll
                for (int j = 0; j < 4; j++)
                    acc[i][j] = fmaf(a[i], b[j], acc[i][j]);
        }
        __syncthreads();
    }
#pragma unroll
    for (int i = 0; i < 4; i++) {
        int gm = m_base + tm * 4 + i;
        if (gm >= M) continue;
#pragma unroll
        for (int j = 0; j < 4; j++) {
            int gn = n_base + tn * 4 + j;
            if (gn >= N) continue;
            float v = acc[i][j];
            if (bias1) v += bias1[gn];
            if (act == 1) v = tanhf(v);
            else if (act == 2) v = expf(v);
            C[(size_t)gm * N + gn] = v;
        }
    }
}

// ---------------------------------------------------------------------------
__global__ __launch_bounds__(256) void conv_f2b(
    const float* __restrict__ src, short* __restrict__ dst, int n)
{
    int i = blockIdx.x * 256 + threadIdx.x;
    if (i < n) dst[i] = f2b(src[i]);
}
__global__ __launch_bounds__(256) void conv_f2b_pad(
    const float* __restrict__ src, short* __restrict__ dst,
    int rows, int kin, int kp)
{
    int i = blockIdx.x * 256 + threadIdx.x;
    if (i < rows * kp) {
        int r = i / kp, k = i % kp;
        dst[i] = (k < kin) ? f2b(src[(size_t)r * kin + k]) : (short)0;
    }
}

__global__ __launch_bounds__(256) void attn_alpha(
    const float* __restrict__ E, float* __restrict__ AB)
{
    const int b = blockIdx.x, tid = threadIdx.x;
    __shared__ float red[256];
    __shared__ float adj[152];
    float v = 0.f;
    if (tid < 150) {
        int d = tid / F_, j = tid % F_;
        v = E[((size_t)d * B_ + b) * F_ + j];
    }
    red[tid] = v; __syncthreads();
    for (int s2 = 128; s2 > 0; s2 >>= 1) {
        if (tid < s2) red[tid] += red[tid + s2];
        __syncthreads();
    }
    float total = red[0]; __syncthreads();
    float alpha = v / total;
    float m = (tid < 150 && alpha >= 0.1f) ? 1.f : 0.f;
    red[tid] = m; __syncthreads();
    for (int s2 = 128; s2 > 0; s2 >>= 1) {
        if (tid < s2) red[tid] += red[tid + s2];
        __syncthreads();
    }
    float cnt = red[0]; __syncthreads();
    red[tid] = m * alpha; __syncthreads();
    for (int s2 = 128; s2 > 0; s2 >>= 1) {
        if (tid < s2) red[tid] += red[tid + s2];
        __syncthreads();
    }
    float selsum = red[0]; __syncthreads();
    float selmean = selsum / fmaxf(cnt, 1.f);
    if (tid < 150) adj[tid] = (m > 0.f) ? selmean : alpha;
    __syncthreads();
    if (tid < F_) AB[(size_t)b * F_ + tid] = 0.5f * (adj[tid] + adj[F_ + tid]);
}

__global__ __launch_bounds__(256) void scale_xb(
    const float* __restrict__ x, const float* __restrict__ AB,
    short* __restrict__ xb)
{
    int i = blockIdx.x * 256 + threadIdx.x;
    if (i < TB_ * KP_) {
        int r = i >> 7, k = i & 127;
        if (k < F_) {
            int b = r % B_;
            xb[i] = f2b(x[(size_t)r * F_ + k] * AB[(size_t)b * F_ + k]);
        } else xb[i] = 0;
    }
}

// ---------------------------------------------------------------------------
extern "C" void kernel_launch(void* const* d_in, const int* in_sizes, int n_in,
                              void* d_out, int out_size, void* d_ws, size_t ws_size,
                              hipStream_t stream)
{
    (void)in_sizes; (void)n_in; (void)out_size; (void)ws_size;
    const float* x       = (const float*)d_in[0];
    const float* h0      = (const float*)d_in[1];
    const float* c0      = (const float*)d_in[2];
    const float* sa_Wih  = (const float*)d_in[3];
    const float* sa_Whh  = (const float*)d_in[4];
    const float* sa_bih  = (const float*)d_in[5];
    const float* sa_bhh  = (const float*)d_in[6];
    const float* m0_Wih  = (const float*)d_in[7];
    const float* m0_Whh  = (const float*)d_in[8];
    const float* m0_bih  = (const float*)d_in[9];
    const float* m0_bhh  = (const float*)d_in[10];
    const float* mL_Wih  = (const float*)d_in[11];
    const float* mL_Whh  = (const float*)d_in[12];
    const float* mL_bih  = (const float*)d_in[13];
    const float* mL_bhh  = (const float*)d_in[14];
    const float* safc1_W = (const float*)d_in[15];
    const float* safc1_b = (const float*)d_in[16];
    const float* safc2_W = (const float*)d_in[17];
    const float* safc2_b = (const float*)d_in[18];
    const float* fc1_W   = (const float*)d_in[19];
    const float* fc1_b   = (const float*)d_in[20];

    char* cur = (char*)d_ws;
    auto alloc = [&](size_t bytes) {
        char* p = cur; cur += (bytes + 255) & ~(size_t)255; return p;
    };
    float*    XW   = (float*)alloc((size_t)2 * TB_ * G4_ * 4);   // packed
    float*    T1b  = (float*)alloc(2 * B_ * H_ * 4);
    float*    Eb   = (float*)alloc(2 * B_ * F_ * 4);
    float*    AB   = (float*)alloc(B_ * F_ * 4);
    float*    saHf = (float*)alloc(2 * B_ * H_ * 4);
    short*    xb   = (short*)alloc((size_t)TB_ * KP_ * 2);
    short*    Y0b  = (short*)alloc((size_t)TB_ * 2 * H_ * 2);
    short*    Y1b  = (short*)alloc((size_t)TB_ * 2 * H_ * 2);
    short*    Ht   = (short*)alloc((size_t)2 * 2 * B_ * H_ * 2);
    short*    Wpk  = (short*)alloc((size_t)2 * G4_ * H_ * 2);
    short*    Wihb = (short*)alloc((size_t)2 * G4_ * KP_ * 2);
    short*    WihbL= (short*)alloc((size_t)2 * G4_ * 2 * H_ * 2);
    short*    fc1b = (short*)alloc((size_t)H_ * 2 * H_ * 2);
    unsigned* bar  = (unsigned*)alloc(1024);

    auto cv = [&](const float* s, short* d, int n) {
        conv_f2b<<<(n + 255) / 256, 256, 0, stream>>>(s, d, n);
    };
    auto g16 = [&](const short* Ap, const short* Bp, float* Cp, float* Pp,
                   int M, int N, int K, const float* b1, const float* b2) {
        gemm_bf16<<<dim3(N / 128, M / 128), 256, 0, stream>>>(Ap, Bp, Cp, Pp, M, N, K, b1, b2);
    };
    auto phase = [&](const float* Whh_p, const float* h0p, const float* c0p,
                     short* Yout, int pidx) {
        pack_whh<<<(2 * G4_ * H_ + 255) / 256, 256, 0, stream>>>(Whh_p, Wpk);
        init_phase<<<256, 256, 0, stream>>>(h0p, Ht, bar, pidx == 0 ? 1 : 0);
        lstm_phase<<<dim3(32, 2), 256, 0, stream>>>(XW, Wpk, Ht, c0p, Yout, bar, pidx);
    };

    cv(fc1_W, fc1b, H_ * 2 * H_);

    // ---- Phase A: SA BiLSTM ----
    conv_f2b_pad<<<(TB_ * KP_ + 255) / 256, 256, 0, stream>>>(x, xb, TB_, F_, KP_);
    conv_f2b_pad<<<(2 * G4_ * KP_ + 255) / 256, 256, 0, stream>>>(sa_Wih, Wihb, 2 * G4_, F_, KP_);
    for (int d = 0; d < 2; d++)
        g16(xb, Wihb + (size_t)d * G4_ * KP_, nullptr, XW + (size_t)d * TB_ * G4_,
            TB_, G4_, KP_, sa_bih + d * G4_, sa_bhh + d * G4_);
    phase(sa_Whh, h0, c0, nullptr, 0);
    ht_to_f32<<<256, 256, 0, stream>>>(Ht, saHf);   // final h in buffer 0
    gemm_bt<<<dim3(8, 2), 256, 0, stream>>>(saHf, safc1_W, T1b, 2 * B_, H_, H_, safc1_b, 1);
    gemm_bt<<<dim3(2, 2), 256, 0, stream>>>(T1b, safc2_W, Eb, 2 * B_, F_, H_, safc2_b, 2);
    attn_alpha<<<B_, 256, 0, stream>>>(Eb, AB);
    scale_xb<<<(TB_ * KP_ + 255) / 256, 256, 0, stream>>>(x, AB, xb);

    // ---- Phase B: main layer 0 ----
    conv_f2b_pad<<<(2 * G4_ * KP_ + 255) / 256, 256, 0, stream>>>(m0_Wih, Wihb, 2 * G4_, F_, KP_);
    for (int d = 0; d < 2; d++)
        g16(xb, Wihb + (size_t)d * G4_ * KP_, nullptr, XW + (size_t)d * TB_ * G4_,
            TB_, G4_, KP_, m0_bih + d * G4_, m0_bhh + d * G4_);
    phase(m0_Whh, h0, c0, Y0b, 1);

    // ---- Phase C: main layer 1 ----
    cv(mL_Wih, WihbL, 2 * G4_ * 2 * H_);
    for (int d = 0; d < 2; d++)
        g16(Y0b, WihbL + (size_t)d * G4_ * 2 * H_, nullptr, XW + (size_t)d * TB_ * G4_,
            TB_, G4_, 2 * H_, mL_bih + d * G4_, mL_bhh + d * G4_);
    phase(mL_Whh, h0 + 2 * B_ * H_, c0 + 2 * B_ * H_, Y1b, 2);

    // ---- Phase D: main layer 2 ----
    cv(mL_Wih + (size_t)2 * G4_ * 2 * H_, WihbL, 2 * G4_ * 2 * H_);
    for (int d = 0; d < 2; d++)
        g16(Y1b, WihbL + (size_t)d * G4_ * 2 * H_, nullptr, XW + (size_t)d * TB_ * G4_,
            TB_, G4_, 2 * H_, mL_bih + (2 + d) * G4_, mL_bhh + (2 + d) * G4_);
    phase(mL_Whh + (size_t)2 * G4_ * H_, h0 + 4 * B_ * H_, c0 + 4 * B_ * H_, Y0b, 3);

    // ---- FC1 ----
    g16(Y0b, fc1b, (float*)d_out, nullptr, TB_, H_, 2 * H_, fc1_b, nullptr);
}

// Round 7
// 4145.109 us; speedup vs baseline: 1.3112x; 1.3112x over previous
//
#include <hip/hip_runtime.h>
#include <cstddef>

#define T_  128
#define B_  64
#define F_  75
#define H_  512
#define G4_ 2048
#define TB_ (T_ * B_)
#define KP_ 128   // padded K for F=75 inputs

typedef __bf16 bf16x8 __attribute__((ext_vector_type(8)));
typedef float  f32x4  __attribute__((ext_vector_type(4)));
typedef unsigned long long u64;
typedef unsigned long long __attribute__((may_alias)) u64a;

__device__ __forceinline__ short f2b(float x) {
    union { float f; unsigned u; } v; v.f = x;
    return (short)((v.u + 0x7fffu + ((v.u >> 16) & 1u)) >> 16);
}
__device__ __forceinline__ float b2f(short s) {
    union { float f; unsigned u; } v; v.u = ((unsigned)(unsigned short)s) << 16;
    return v.f;
}
__device__ __forceinline__ void gload16(const void* g, void* l) {
    __builtin_amdgcn_global_load_lds(
        (const __attribute__((address_space(1))) void*)g,
        (__attribute__((address_space(3))) void*)l, 16, 0, 0);
}
__device__ __forceinline__ float fsig(float x) {
    return __builtin_amdgcn_rcpf(1.f + __expf(-x));
}
__device__ __forceinline__ float ftanh(float x) {
    return 1.f - 2.f * __builtin_amdgcn_rcpf(1.f + __expf(2.f * x));
}

// ---------------------------------------------------------------------------
// bf16 MFMA GEMM. If P != null: write fp32 results into the step-kernel's
// packed XW layout  P[t][ub(32)][r(4)][tidS(256)][g(4)]  (biases included).
// Else: C(M,N) fp32 row-major.
// ---------------------------------------------------------------------------
__global__ __launch_bounds__(256) void gemm_bf16(
    const short* __restrict__ A, const short* __restrict__ Bm,
    float* __restrict__ C, float* __restrict__ P, int M, int N, int K,
    const float* __restrict__ bias1, const float* __restrict__ bias2)
{
    __shared__ short As[4096];
    __shared__ short Bs[4096];
    const int tid = threadIdx.x;
    const int m_base = blockIdx.y * 128;
    const int n_base = blockIdx.x * 128;
    const int w = tid >> 6, lane = tid & 63;
    const int wm = (w >> 1) * 64, wn = (w & 1) * 64;
    const int lm = lane & 15, q = lane >> 4;

    f32x4 acc[4][4];
#pragma unroll
    for (int i = 0; i < 4; i++)
#pragma unroll
        for (int j = 0; j < 4; j++)
#pragma unroll
            for (int r = 0; r < 4; r++) acc[i][j][r] = 0.f;

    const int s0 = tid, s1 = tid + 256;
    const int r0 = s0 & 127, c0 = s0 >> 7;
    const int r1 = s1 & 127, c1 = s1 >> 7;

    for (int k0 = 0; k0 < K; k0 += 32) {
        __syncthreads();
        gload16(A + (size_t)(m_base + r0) * K + k0 + c0 * 8, &As[s0 * 8]);
        gload16(A + (size_t)(m_base + r1) * K + k0 + c1 * 8, &As[s1 * 8]);
        gload16(Bm + (size_t)(n_base + r0) * K + k0 + c0 * 8, &Bs[s0 * 8]);
        gload16(Bm + (size_t)(n_base + r1) * K + k0 + c1 * 8, &Bs[s1 * 8]);
        __syncthreads();
        bf16x8 af[4], bfv[4];
#pragma unroll
        for (int i = 0; i < 4; i++) {
            af[i]  = *(const bf16x8*)&As[((q * 128) + wm + i * 16 + lm) * 8];
            bfv[i] = *(const bf16x8*)&Bs[((q * 128) + wn + i * 16 + lm) * 8];
        }
#pragma unroll
        for (int i = 0; i < 4; i++)
#pragma unroll
            for (int j = 0; j < 4; j++)
                acc[i][j] = __builtin_amdgcn_mfma_f32_16x16x32_bf16(
                    af[i], bfv[j], acc[i][j], 0, 0, 0);
    }

#pragma unroll
    for (int i = 0; i < 4; i++) {
#pragma unroll
        for (int j = 0; j < 4; j++) {
            const int gm0 = m_base + wm + i * 16 + q * 4;
            const int gn = n_base + wn + j * 16 + lm;
            float bb = (bias1 ? bias1[gn] : 0.f) + (bias2 ? bias2[gn] : 0.f);
            if (P) {
                const int g = gn >> 9, u = gn & 511;
                const int ub = u >> 4, lmu = u & 15;
#pragma unroll
                for (int r = 0; r < 4; r++) {
                    const int gm = gm0 + r;
                    const int t = gm >> 6, b = gm & 63;
                    const int tidS = (b >> 4) * 64 + ((b >> 2) & 3) * 16 + lmu;
                    size_t idx = ((((size_t)t * 32 + ub) * 4 + (b & 3)) * 256 + tidS) * 4 + g;
                    P[idx] = acc[i][j][r] + bb;
                }
            } else {
#pragma unroll
                for (int r = 0; r < 4; r++)
                    C[(size_t)(gm0 + r) * N + gn] = acc[i][j][r] + bb;
            }
        }
    }
}

// ---------------------------------------------------------------------------
// Pack Whh (2,4H,H) fp32 -> bf16 B-fragments:
// Wpk[dir][ub(32)][g(4)][it(16)][lane(64)][8]
// ---------------------------------------------------------------------------
__global__ __launch_bounds__(256) void pack_whh(
    const float* __restrict__ W, short* __restrict__ Wpk)
{
    int i = blockIdx.x * 256 + threadIdx.x;
    if (i >= 2 * G4_ * H_) return;
    int e = i & 7, lane = (i >> 3) & 63, it = (i >> 9) & 15;
    int g = (i >> 13) & 3, ub = (i >> 15) & 31, dir = (i >> 20) & 1;
    int lm = lane & 15, qq = lane >> 4;
    float v = W[((size_t)dir * G4_ + g * H_ + ub * 16 + lm) * H_
                + it * 32 + qq * 8 + e];
    Wpk[i] = f2b(v);
}

// ---------------------------------------------------------------------------
// bar layout (u32): [0..63] per-BLOCK step tags: dir*32 + ub (one 128B line
// per dir). Tags zeroed only at phase 0 (monotonic across phases).
// ---------------------------------------------------------------------------
__global__ __launch_bounds__(256) void init_phase(
    const float* __restrict__ h0s, short* __restrict__ Ht,
    unsigned* __restrict__ bar, int zero_bar)
{
    int i = blockIdx.x * 256 + threadIdx.x;
    if (i < 2 * B_ * H_) Ht[i] = f2b(h0s[i]);
    if (zero_bar && i < 64) bar[i] = 0;
}

__global__ __launch_bounds__(256) void ht_to_f32(
    const short* __restrict__ Ht0, float* __restrict__ out)
{
    int i = blockIdx.x * 256 + threadIdx.x;
    if (i < 2 * B_ * H_) out[i] = b2f(Ht0[i]);
}

// ---------------------------------------------------------------------------
// Persistent phase kernel. grid (32, 2): block = 16 units, 1 dir.
// Whh in 64KB LDS (B-frag order). All cross-block traffic agent-scope.
// R1 protocol (best measured: 751us/phase) made SOUND via LDS arrive:
//  - each wave publishes its 16 batch rows, drains its OWN vmcnt, then
//    bumps a monotonic LDS arrival counter (ds_add, intra-CU).
//  - wave0 spins on the LDS counter until all 4 waves' drains are acked
//    (~100cy), THEN stores the single per-block tag (32 tags/dir = one
//    128B line, plain agent store, no RMW).  tag => all h-stores acked.
//  - wave0 alone polls the 32 tags (check-first); waves 1-3 park on ONE
//    __syncthreads. Y-store + XW-prefetch sit between tag and poll.
//  - Tb transpose tile wave-private; may_alias u64 read + compiler fences
//    (R2 NaN lesson: never type-pun LDS without killing TBAA).
// ---------------------------------------------------------------------------
__global__ __launch_bounds__(256, 1) void lstm_phase(
    const float* __restrict__ XW,   // packed (2,T,32,4,256,4) fp32
    const short* __restrict__ Wpk,  // packed Whh bf16
    short* __restrict__ Ht,         // (2buf,2dir,64b,512u) bf16
    const float* __restrict__ c0p,  // (2,B,H) fp32 initial c
    short* __restrict__ Y,          // (T,B,2H) bf16 or null
    unsigned* __restrict__ bar, int phase)
{
    __shared__ short Ws[32768];     // 64 KB packed weights
    __shared__ short Tb[64 * 24];   // transpose buffer (48B row stride)
    __shared__ unsigned arrv;       // monotonic per-phase arrival counter
    const int dir = blockIdx.y, ub = blockIdx.x, u0 = ub * 16;
    const int tid = threadIdx.x, w = tid >> 6, lane = tid & 63;
    const int lm = lane & 15, q = lane >> 4;

    if (tid == 0) arrv = 0;

    const short* wsrc = Wpk + (size_t)(dir * 32 + ub) * 32768;
#pragma unroll
    for (int p = 0; p < 16; p++)
        gload16(wsrc + (tid + 256 * p) * 8, &Ws[(tid + 256 * p) * 8]);

    const int b0 = w * 16 + q * 4;   // this lane's 4 batch rows
    const int u = u0 + lm;           // this lane's hidden unit
    unsigned* slots = bar + dir * 32;

    float c[4];
    f32x4 xw[4];                     // [r] -> 4 gates
#pragma unroll
    for (int r = 0; r < 4; r++)
        c[r] = c0p[(size_t)dir * B_ * H_ + (size_t)(b0 + r) * H_ + u];
    {
        const int t0 = dir ? (T_ - 1) : 0;
        const float* xp = XW + ((size_t)dir * T_ + t0) * (B_ * G4_) + (size_t)ub * 4096;
#pragma unroll
        for (int r = 0; r < 4; r++)
            xw[r] = *(const f32x4*)(xp + r * 1024 + tid * 4);
    }
    __syncthreads();   // Ws resident + arrv init visible

    for (int s = 0; s < T_; s++) {
        const int t = dir ? (T_ - 1 - s) : s;
        const short* Hc = Ht + ((size_t)((s & 1) * 2 + dir) << 15);

        // ---- h A-fragments (full h vector), agent-scope bulk gather
        u64 hq[32];
        const short* hrow = Hc + (w * 16 + lm) * 512 + q * 8;
#pragma unroll
        for (int it = 0; it < 16; it++) {
            const u64* hp = (const u64*)(hrow + it * 32);
            hq[2 * it]     = __hip_atomic_load((u64*)hp,     __ATOMIC_RELAXED, __HIP_MEMORY_SCOPE_AGENT);
            hq[2 * it + 1] = __hip_atomic_load((u64*)hp + 1, __ATOMIC_RELAXED, __HIP_MEMORY_SCOPE_AGENT);
        }

        f32x4 acc[4];
#pragma unroll
        for (int g = 0; g < 4; g++)
#pragma unroll
            for (int r = 0; r < 4; r++) acc[g][r] = 0.f;

#pragma unroll
        for (int it = 0; it < 16; it++) {
            union { u64 q2[2]; bf16x8 v; } ua;
            ua.q2[0] = hq[2 * it]; ua.q2[1] = hq[2 * it + 1];
#pragma unroll
            for (int g = 0; g < 4; g++) {
                bf16x8 bv = *(const bf16x8*)&Ws[((g * 16 + it) * 64 + lane) * 8];
                acc[g] = __builtin_amdgcn_mfma_f32_16x16x32_bf16(ua.v, bv, acc[g], 0, 0, 0);
            }
        }

        // ---- pointwise gates; h -> LDS transpose tile (wave-private rows)
#pragma unroll
        for (int r = 0; r < 4; r++) {
            float gi = acc[0][r] + xw[r][0];
            float gf = acc[1][r] + xw[r][1];
            float gg = acc[2][r] + xw[r][2];
            float go = acc[3][r] + xw[r][3];
            float cc = fsig(gf) * c[r] + fsig(gi) * ftanh(gg);
            c[r] = cc;
            Tb[(b0 + r) * 24 + lm] = f2b(fsig(go) * ftanh(cc));
        }
        __asm__ volatile("" ::: "memory");   // order Tb writes before Tb read

        // ---- per-wave publish (u64 per thread); own drain; LDS arrive
        const int b = tid >> 2, qd = tid & 3;      // b in [16w, 16w+16)
        u64 v0 = *(const u64a*)&Tb[b * 24 + qd * 4];
        {
            short* Hn = Ht + ((size_t)(((s + 1) & 1) * 2 + dir) << 15);
            __hip_atomic_store((u64*)(Hn + b * 512 + u0 + qd * 4), v0,
                               __ATOMIC_RELAXED, __HIP_MEMORY_SCOPE_AGENT);
        }
        __asm__ volatile("s_waitcnt vmcnt(0)" ::: "memory");
        if (lane == 0)
            __hip_atomic_fetch_add(&arrv, 1u, __ATOMIC_RELAXED,
                                   __HIP_MEMORY_SCOPE_WORKGROUP);

        const unsigned tgt = (unsigned)(phase * T_ + s + 1);
        if (w == 0) {
            // wait all 4 waves' drains acked, then publish the block tag
            const unsigned a4 = 4u * (unsigned)(s + 1);
            while (__hip_atomic_load(&arrv, __ATOMIC_RELAXED,
                                     __HIP_MEMORY_SCOPE_WORKGROUP) < a4) {}
            if (lane == 0)
                __hip_atomic_store(&slots[ub], tgt,
                                   __ATOMIC_RELAXED, __HIP_MEMORY_SCOPE_AGENT);
        }

        // ---- Y store + next-step XW prefetch (overlap the poll window)
        if (Y)
            *(u64a*)(Y + ((size_t)t * B_ + b) * (2 * H_) + dir * H_ + u0 + qd * 4) = v0;
        if (s < T_ - 1) {
            const int tn = dir ? (T_ - 2 - s) : (s + 1);
            const float* xp = XW + ((size_t)dir * T_ + tn) * (B_ * G4_) + (size_t)ub * 4096;
#pragma unroll
            for (int r = 0; r < 4; r++)
                xw[r] = *(const f32x4*)(xp + r * 1024 + tid * 4);

            // ---- wave0 polls the dir's 32 tags (check-first)
            if (w == 0) {
                unsigned v;
                for (;;) {
                    v = (lane < 32)
                        ? __hip_atomic_load(&slots[lane], __ATOMIC_RELAXED, __HIP_MEMORY_SCOPE_AGENT)
                        : tgt;
                    if (__all(v >= tgt)) break;
                    __builtin_amdgcn_s_sleep(1);
                }
            }
            __syncthreads();   // release waves 1-3 into the next step
        }
    }
}

// ---------------------------------------------------------------------------
// fp32 GEMM for tiny attention matmuls (bounds-checked), act 0/1/2
// ---------------------------------------------------------------------------
__global__ __launch_bounds__(256) void gemm_bt(
    const float* __restrict__ A, const float* __restrict__ Bm,
    float* __restrict__ C, int M, int N, int K,
    const float* __restrict__ bias1, int act)
{
    __shared__ float As[16][68];
    __shared__ float Bs[16][68];
    const int tid = threadIdx.x;
    const int m_base = blockIdx.y * 64;
    const int n_base = blockIdx.x * 64;
    const int tm = tid >> 4, tn = tid & 15;
    float acc[4][4] = {};

    for (int k0 = 0; k0 < K; k0 += 16) {
#pragma unroll
        for (int i = 0; i < 4; i++) {
            int idx = tid * 4 + i;
            int r = idx >> 4, kk = idx & 15;
            int gm = m_base + r, gk = k0 + kk;
            As[kk][r] = (gm < M && gk < K) ? A[(size_t)gm * K + gk] : 0.f;
            int gn = n_base + r;
            Bs[kk][r] = (gn < N && gk < K) ? Bm[(size_t)gn * K + gk] : 0.f;
        }
        __syncthreads();
#pragma unroll
        for (int kk = 0; kk < 16; kk++) {
            float4 av = *(const float4*)&As[kk][tm * 4];
            float4 bv = *(const float4*)&Bs[kk][tn * 4];
            float a[4] = {av.x, av.y, av.z, av.w};
            float b[4] = {bv.x, bv.y, bv.z, bv.w};
#pragma unroll
            for (int i = 0; i < 4; i++)
#pragma unroll
                for (int j = 0; j < 4; j++)
                    acc[i][j] = fmaf(a[i], b[j], acc[i][j]);
        }
        __syncthreads();
    }
#pragma unroll
    for (int i = 0; i < 4; i++) {
        int gm = m_base + tm * 4 + i;
        if (gm >= M) continue;
#pragma unroll
        for (int j = 0; j < 4; j++) {
            int gn = n_base + tn * 4 + j;
            if (gn >= N) continue;
            float v = acc[i][j];
            if (bias1) v += bias1[gn];
            if (act == 1) v = tanhf(v);
            else if (act == 2) v = expf(v);
            C[(size_t)gm * N + gn] = v;
        }
    }
}

// ---------------------------------------------------------------------------
__global__ __launch_bounds__(256) void conv_f2b(
    const float* __restrict__ src, short* __restrict__ dst, int n)
{
    int i = blockIdx.x * 256 + threadIdx.x;
    if (i < n) dst[i] = f2b(src[i]);
}
__global__ __launch_bounds__(256) void conv_f2b_pad(
    const float* __restrict__ src, short* __restrict__ dst,
    int rows, int kin, int kp)
{
    int i = blockIdx.x * 256 + threadIdx.x;
    if (i < rows * kp) {
        int r = i / kp, k = i % kp;
        dst[i] = (k < kin) ? f2b(src[(size_t)r * kin + k]) : (short)0;
    }
}

__global__ __launch_bounds__(256) void attn_alpha(
    const float* __restrict__ E, float* __restrict__ AB)
{
    const int b = blockIdx.x, tid = threadIdx.x;
    __shared__ float red[256];
    __shared__ float adj[152];
    float v = 0.f;
    if (tid < 150) {
        int d = tid / F_, j = tid % F_;
        v = E[((size_t)d * B_ + b) * F_ + j];
    }
    red[tid] = v; __syncthreads();
    for (int s2 = 128; s2 > 0; s2 >>= 1) {
        if (tid < s2) red[tid] += red[tid + s2];
        __syncthreads();
    }
    float total = red[0]; __syncthreads();
    float alpha = v / total;
    float m = (tid < 150 && alpha >= 0.1f) ? 1.f : 0.f;
    red[tid] = m; __syncthreads();
    for (int s2 = 128; s2 > 0; s2 >>= 1) {
        if (tid < s2) red[tid] += red[tid + s2];
        __syncthreads();
    }
    float cnt = red[0]; __syncthreads();
    red[tid] = m * alpha; __syncthreads();
    for (int s2 = 128; s2 > 0; s2 >>= 1) {
        if (tid < s2) red[tid] += red[tid + s2];
        __syncthreads();
    }
    float selsum = red[0]; __syncthreads();
    float selmean = selsum / fmaxf(cnt, 1.f);
    if (tid < 150) adj[tid] = (m > 0.f) ? selmean : alpha;
    __syncthreads();
    if (tid < F_) AB[(size_t)b * F_ + tid] = 0.5f * (adj[tid] + adj[F_ + tid]);
}

__global__ __launch_bounds__(256) void scale_xb(
    const float* __restrict__ x, const float* __restrict__ AB,
    short* __restrict__ xb)
{
    int i = blockIdx.x * 256 + threadIdx.x;
    if (i < TB_ * KP_) {
        int r = i >> 7, k = i & 127;
        if (k < F_) {
            int b = r % B_;
            xb[i] = f2b(x[(size_t)r * F_ + k] * AB[(size_t)b * F_ + k]);
        } else xb[i] = 0;
    }
}

// ---------------------------------------------------------------------------
extern "C" void kernel_launch(void* const* d_in, const int* in_sizes, int n_in,
                              void* d_out, int out_size, void* d_ws, size_t ws_size,
                              hipStream_t stream)
{
    (void)in_sizes; (void)n_in; (void)out_size; (void)ws_size;
    const float* x       = (const float*)d_in[0];
    const float* h0      = (const float*)d_in[1];
    const float* c0      = (const float*)d_in[2];
    const float* sa_Wih  = (const float*)d_in[3];
    const float* sa_Whh  = (const float*)d_in[4];
    const float* sa_bih  = (const float*)d_in[5];
    const float* sa_bhh  = (const float*)d_in[6];
    const float* m0_Wih  = (const float*)d_in[7];
    const float* m0_Whh  = (const float*)d_in[8];
    const float* m0_bih  = (const float*)d_in[9];
    const float* m0_bhh  = (const float*)d_in[10];
    const float* mL_Wih  = (const float*)d_in[11];
    const float* mL_Whh  = (const float*)d_in[12];
    const float* mL_bih  = (const float*)d_in[13];
    const float* mL_bhh  = (const float*)d_in[14];
    const float* safc1_W = (const float*)d_in[15];
    const float* safc1_b = (const float*)d_in[16];
    const float* safc2_W = (const float*)d_in[17];
    const float* safc2_b = (const float*)d_in[18];
    const float* fc1_W   = (const float*)d_in[19];
    const float* fc1_b   = (const float*)d_in[20];

    char* cur = (char*)d_ws;
    auto alloc = [&](size_t bytes) {
        char* p = cur; cur += (bytes + 255) & ~(size_t)255; return p;
    };
    float*    XW   = (float*)alloc((size_t)2 * TB_ * G4_ * 4);   // packed
    float*    T1b  = (float*)alloc(2 * B_ * H_ * 4);
    float*    Eb   = (float*)alloc(2 * B_ * F_ * 4);
    float*    AB   = (float*)alloc(B_ * F_ * 4);
    float*    saHf = (float*)alloc(2 * B_ * H_ * 4);
    short*    xb   = (short*)alloc((size_t)TB_ * KP_ * 2);
    short*    Y0b  = (short*)alloc((size_t)TB_ * 2 * H_ * 2);
    short*    Y1b  = (short*)alloc((size_t)TB_ * 2 * H_ * 2);
    short*    Ht   = (short*)alloc((size_t)2 * 2 * B_ * H_ * 2);
    short*    Wpk  = (short*)alloc((size_t)2 * G4_ * H_ * 2);
    short*    Wihb = (short*)alloc((size_t)2 * G4_ * KP_ * 2);
    short*    WihbL= (short*)alloc((size_t)2 * G4_ * 2 * H_ * 2);
    short*    fc1b = (short*)alloc((size_t)H_ * 2 * H_ * 2);
    unsigned* bar  = (unsigned*)alloc(1024);

    auto cv = [&](const float* s, short* d, int n) {
        conv_f2b<<<(n + 255) / 256, 256, 0, stream>>>(s, d, n);
    };
    auto g16 = [&](const short* Ap, const short* Bp, float* Cp, float* Pp,
                   int M, int N, int K, const float* b1, const float* b2) {
        gemm_bf16<<<dim3(N / 128, M / 128), 256, 0, stream>>>(Ap, Bp, Cp, Pp, M, N, K, b1, b2);
    };
    auto phase = [&](const float* Whh_p, const float* h0p, const float* c0p,
                     short* Yout, int pidx) {
        pack_whh<<<(2 * G4_ * H_ + 255) / 256, 256, 0, stream>>>(Whh_p, Wpk);
        init_phase<<<256, 256, 0, stream>>>(h0p, Ht, bar, pidx == 0 ? 1 : 0);
        lstm_phase<<<dim3(32, 2), 256, 0, stream>>>(XW, Wpk, Ht, c0p, Yout, bar, pidx);
    };

    cv(fc1_W, fc1b, H_ * 2 * H_);

    // ---- Phase A: SA BiLSTM ----
    conv_f2b_pad<<<(TB_ * KP_ + 255) / 256, 256, 0, stream>>>(x, xb, TB_, F_, KP_);
    conv_f2b_pad<<<(2 * G4_ * KP_ + 255) / 256, 256, 0, stream>>>(sa_Wih, Wihb, 2 * G4_, F_, KP_);
    for (int d = 0; d < 2; d++)
        g16(xb, Wihb + (size_t)d * G4_ * KP_, nullptr, XW + (size_t)d * TB_ * G4_,
            TB_, G4_, KP_, sa_bih + d * G4_, sa_bhh + d * G4_);
    phase(sa_Whh, h0, c0, nullptr, 0);
    ht_to_f32<<<256, 256, 0, stream>>>(Ht, saHf);   // final h in buffer 0
    gemm_bt<<<dim3(8, 2), 256, 0, stream>>>(saHf, safc1_W, T1b, 2 * B_, H_, H_, safc1_b, 1);
    gemm_bt<<<dim3(2, 2), 256, 0, stream>>>(T1b, safc2_W, Eb, 2 * B_, F_, H_, safc2_b, 2);
    attn_alpha<<<B_, 256, 0, stream>>>(Eb, AB);
    scale_xb<<<(TB_ * KP_ + 255) / 256, 256, 0, stream>>>(x, AB, xb);

    // ---- Phase B: main layer 0 ----
    conv_f2b_pad<<<(2 * G4_ * KP_ + 255) / 256, 256, 0, stream>>>(m0_Wih, Wihb, 2 * G4_, F_, KP_);
    for (int d = 0; d < 2; d++)
        g16(xb, Wihb + (size_t)d * G4_ * KP_, nullptr, XW + (size_t)d * TB_ * G4_,
            TB_, G4_, KP_, m0_bih + d * G4_, m0_bhh + d * G4_);
    phase(m0_Whh, h0, c0, Y0b, 1);

    // ---- Phase C: main layer 1 ----
    cv(mL_Wih, WihbL, 2 * G4_ * 2 * H_);
    for (int d = 0; d < 2; d++)
        g16(Y0b, WihbL + (size_t)d * G4_ * 2 * H_, nullptr, XW + (size_t)d * TB_ * G4_,
            TB_, G4_, 2 * H_, mL_bih + d * G4_, mL_bhh + d * G4_);
    phase(mL_Whh, h0 + 2 * B_ * H_, c0 + 2 * B_ * H_, Y1b, 2);

    // ---- Phase D: main layer 2 ----
    cv(mL_Wih + (size_t)2 * G4_ * 2 * H_, WihbL, 2 * G4_ * 2 * H_);
    for (int d = 0; d < 2; d++)
        g16(Y1b, WihbL + (size_t)d * G4_ * 2 * H_, nullptr, XW + (size_t)d * TB_ * G4_,
            TB_, G4_, 2 * H_, mL_bih + (2 + d) * G4_, mL_bhh + (2 + d) * G4_);
    phase(mL_Whh + (size_t)2 * G4_ * H_, h0 + 4 * B_ * H_, c0 + 4 * B_ * H_, Y0b, 3);

    // ---- FC1 ----
    g16(Y0b, fc1b, (float*)d_out, nullptr, TB_, H_, 2 * H_, fc1_b, nullptr);
}

// Round 8
// 4143.734 us; speedup vs baseline: 1.3116x; 1.0003x over previous
//
#include <hip/hip_runtime.h>
#include <cstddef>

#define T_  128
#define B_  64
#define F_  75
#define H_  512
#define G4_ 2048
#define TB_ (T_ * B_)
#define KP_ 128   // padded K for F=75 inputs

typedef __bf16 bf16x8 __attribute__((ext_vector_type(8)));
typedef float  f32x4  __attribute__((ext_vector_type(4)));
typedef unsigned long long u64;
typedef unsigned long long __attribute__((may_alias)) u64a;

__device__ __forceinline__ short f2b(float x) {
    union { float f; unsigned u; } v; v.f = x;
    return (short)((v.u + 0x7fffu + ((v.u >> 16) & 1u)) >> 16);
}
__device__ __forceinline__ float b2f(short s) {
    union { float f; unsigned u; } v; v.u = ((unsigned)(unsigned short)s) << 16;
    return v.f;
}
__device__ __forceinline__ void gload16(const void* g, void* l) {
    __builtin_amdgcn_global_load_lds(
        (const __attribute__((address_space(1))) void*)g,
        (__attribute__((address_space(3))) void*)l, 16, 0, 0);
}
__device__ __forceinline__ float fsig(float x) {
    return __builtin_amdgcn_rcpf(1.f + __expf(-x));
}
__device__ __forceinline__ float ftanh(float x) {
    return 1.f - 2.f * __builtin_amdgcn_rcpf(1.f + __expf(2.f * x));
}

// ---------------------------------------------------------------------------
// bf16 MFMA GEMM. If P != null: write fp32 results into the step-kernel's
// packed XW layout  P[t][ub(32)][r(4)][tidS(256)][g(4)]  (biases included).
// Else: C(M,N) fp32 row-major.
// ---------------------------------------------------------------------------
__global__ __launch_bounds__(256) void gemm_bf16(
    const short* __restrict__ A, const short* __restrict__ Bm,
    float* __restrict__ C, float* __restrict__ P, int M, int N, int K,
    const float* __restrict__ bias1, const float* __restrict__ bias2)
{
    __shared__ short As[4096];
    __shared__ short Bs[4096];
    const int tid = threadIdx.x;
    const int m_base = blockIdx.y * 128;
    const int n_base = blockIdx.x * 128;
    const int w = tid >> 6, lane = tid & 63;
    const int wm = (w >> 1) * 64, wn = (w & 1) * 64;
    const int lm = lane & 15, q = lane >> 4;

    f32x4 acc[4][4];
#pragma unroll
    for (int i = 0; i < 4; i++)
#pragma unroll
        for (int j = 0; j < 4; j++)
#pragma unroll
            for (int r = 0; r < 4; r++) acc[i][j][r] = 0.f;

    const int s0 = tid, s1 = tid + 256;
    const int r0 = s0 & 127, c0 = s0 >> 7;
    const int r1 = s1 & 127, c1 = s1 >> 7;

    for (int k0 = 0; k0 < K; k0 += 32) {
        __syncthreads();
        gload16(A + (size_t)(m_base + r0) * K + k0 + c0 * 8, &As[s0 * 8]);
        gload16(A + (size_t)(m_base + r1) * K + k0 + c1 * 8, &As[s1 * 8]);
        gload16(Bm + (size_t)(n_base + r0) * K + k0 + c0 * 8, &Bs[s0 * 8]);
        gload16(Bm + (size_t)(n_base + r1) * K + k0 + c1 * 8, &Bs[s1 * 8]);
        __syncthreads();
        bf16x8 af[4], bfv[4];
#pragma unroll
        for (int i = 0; i < 4; i++) {
            af[i]  = *(const bf16x8*)&As[((q * 128) + wm + i * 16 + lm) * 8];
            bfv[i] = *(const bf16x8*)&Bs[((q * 128) + wn + i * 16 + lm) * 8];
        }
#pragma unroll
        for (int i = 0; i < 4; i++)
#pragma unroll
            for (int j = 0; j < 4; j++)
                acc[i][j] = __builtin_amdgcn_mfma_f32_16x16x32_bf16(
                    af[i], bfv[j], acc[i][j], 0, 0, 0);
    }

#pragma unroll
    for (int i = 0; i < 4; i++) {
#pragma unroll
        for (int j = 0; j < 4; j++) {
            const int gm0 = m_base + wm + i * 16 + q * 4;
            const int gn = n_base + wn + j * 16 + lm;
            float bb = (bias1 ? bias1[gn] : 0.f) + (bias2 ? bias2[gn] : 0.f);
            if (P) {
                const int g = gn >> 9, u = gn & 511;
                const int ub = u >> 4, lmu = u & 15;
#pragma unroll
                for (int r = 0; r < 4; r++) {
                    const int gm = gm0 + r;
                    const int t = gm >> 6, b = gm & 63;
                    const int tidS = (b >> 4) * 64 + ((b >> 2) & 3) * 16 + lmu;
                    size_t idx = ((((size_t)t * 32 + ub) * 4 + (b & 3)) * 256 + tidS) * 4 + g;
                    P[idx] = acc[i][j][r] + bb;
                }
            } else {
#pragma unroll
                for (int r = 0; r < 4; r++)
                    C[(size_t)(gm0 + r) * N + gn] = acc[i][j][r] + bb;
            }
        }
    }
}

// ---------------------------------------------------------------------------
// Pack Whh (2,4H,H) fp32 -> bf16 B-fragments:
// Wpk[dir][ub(32)][g(4)][it(16)][lane(64)][8]
// ---------------------------------------------------------------------------
__global__ __launch_bounds__(256) void pack_whh(
    const float* __restrict__ W, short* __restrict__ Wpk)
{
    int i = blockIdx.x * 256 + threadIdx.x;
    if (i >= 2 * G4_ * H_) return;
    int e = i & 7, lane = (i >> 3) & 63, it = (i >> 9) & 15;
    int g = (i >> 13) & 3, ub = (i >> 15) & 31, dir = (i >> 20) & 1;
    int lm = lane & 15, qq = lane >> 4;
    float v = W[((size_t)dir * G4_ + g * H_ + ub * 16 + lm) * H_
                + it * 32 + qq * 8 + e];
    Wpk[i] = f2b(v);
}

// ---------------------------------------------------------------------------
// bar layout (u32): [0..63] per-BLOCK step tags: dir*32 + ub. Tags monotonic
// across phases within one launch; zeroed at launch start.
// ---------------------------------------------------------------------------
__global__ __launch_bounds__(256) void init_phase(
    const float* __restrict__ h0s, short* __restrict__ Ht,
    unsigned* __restrict__ bar, int zero_bar)
{
    int i = blockIdx.x * 256 + threadIdx.x;
    if (i < 2 * B_ * H_) Ht[i] = f2b(h0s[i]);
    if (zero_bar && i < 64) bar[i] = 0;
}

// overlap path: init ALL phase Ht buffers + bar in one dispatch
__global__ __launch_bounds__(256) void prep_init(
    const float* __restrict__ h0, short* __restrict__ HtA,
    short* __restrict__ HtB, short* __restrict__ HtC, short* __restrict__ HtD,
    unsigned* __restrict__ bar)
{
    int i = blockIdx.x * 256 + threadIdx.x;
    if (i < 2 * B_ * H_) {
        short vA = f2b(h0[i]);
        HtA[i] = vA;
        HtB[i] = vA;
        HtC[i] = f2b(h0[2 * B_ * H_ + i]);
        HtD[i] = f2b(h0[4 * B_ * H_ + i]);
    }
    if (i < 64) bar[i] = 0;
}

__global__ __launch_bounds__(256) void ht_to_f32(
    const short* __restrict__ Ht0, float* __restrict__ out)
{
    int i = blockIdx.x * 256 + threadIdx.x;
    if (i < 2 * B_ * H_) out[i] = b2f(Ht0[i]);
}

// ---------------------------------------------------------------------------
// Persistent phase kernel (R7 protocol, 750us/phase measured) + optional
// HELPER blocks (blockIdx.x >= 32) that overlap the NEXT phase's K=1024
// GEMM with this phase's recurrence, consuming Y per-timestep via the same
// tag line.  job: 0 = none, 1 = packed-XW GEMM (per-dir), 2 = FC1 -> C.
// Y stores are agent-scope BEFORE the drain when job!=0 (tag certifies Y).
// ---------------------------------------------------------------------------
__global__ __launch_bounds__(256, 1) void lstm_phase(
    const float* __restrict__ XW,   // packed (2,T,32,4,256,4) fp32
    const short* __restrict__ Wpk,  // packed Whh bf16
    short* __restrict__ Ht,         // (2buf,2dir,64b,512u) bf16
    const float* __restrict__ c0p,  // (2,B,H) fp32 initial c
    short* __restrict__ Y,          // (T,B,2H) bf16 or null
    unsigned* __restrict__ bar, int phase,
    const short* __restrict__ jA, const short* __restrict__ jB,
    float* __restrict__ jP, float* __restrict__ jC,
    const float* __restrict__ jb1, const float* __restrict__ jb2, int job)
{
    __shared__ short Ws[32768];     // rec: 64KB weights | helper: As/Bs union
    __shared__ short Tb[64 * 24];
    __shared__ unsigned arrv;
    const int tid = threadIdx.x, w = tid >> 6, lane = tid & 63;
    const int lm = lane & 15, q = lane >> 4;

    if (blockIdx.x >= 32) {
        // ================= helper blocks =================
        if (job == 0) return;
        short* As = Ws;
        short* Bs = Ws + 4096;
        const int hh = blockIdx.x - 32;          // 0..63
        const int dirh = blockIdx.y;
        const unsigned pT = (unsigned)(phase * T_);
        const int wm = (w >> 1) * 64, wn = (w & 1) * 64;

        const short* Bop; float* Pd; float* Cd; const float* b1; const float* b2;
        int n_tile, grp, iters, stride;
        if (job == 1) {
            Bop = jB + (size_t)dirh * G4_ * 1024;
            Pd = jP + (size_t)dirh * TB_ * G4_;
            Cd = nullptr;
            b1 = jb1 + dirh * G4_; b2 = jb2 + dirh * G4_;
            n_tile = hh & 15; grp = hh >> 4; iters = 16; stride = 4;
        } else {
            Bop = jB; Pd = nullptr; Cd = jC; b1 = jb1; b2 = nullptr;
            int H2 = dirh * 64 + hh;             // 0..127
            n_tile = H2 & 3; grp = H2 >> 2; iters = 2; stride = 32;
        }
        const int n_base = n_tile * 128;

        for (int it2 = 0; it2 < iters; it2++) {
            int j = grp + stride * it2;
            int k = (j & 1) ? 32 + (j >> 1) : 31 - (j >> 1);   // center-out
            int m_base = k * 128, t0 = 2 * k;
            // readiness: dir0 tags >= pT+t0+2, dir1 tags >= pT+T-t0
            if (w == 0) {
                unsigned tgt = (lane < 32) ? pT + (unsigned)(t0 + 2)
                                           : pT + (unsigned)(T_ - t0);
                int itc = 0;
                for (;;) {
                    unsigned v = __hip_atomic_load(&bar[lane], __ATOMIC_RELAXED,
                                                   __HIP_MEMORY_SCOPE_AGENT);
                    if (__all(v >= tgt)) break;
                    if (++itc > (1 << 19)) break;   // failsafe vs deadlock
                    __builtin_amdgcn_s_sleep(32);
                }
            }
            __syncthreads();

            f32x4 acc[4][4];
#pragma unroll
            for (int i = 0; i < 4; i++)
#pragma unroll
                for (int jj = 0; jj < 4; jj++)
#pragma unroll
                    for (int r = 0; r < 4; r++) acc[i][jj][r] = 0.f;

            const int s0 = tid, s1 = tid + 256;
            const int r0 = s0 & 127, cc0 = s0 >> 7;
            const int r1 = s1 & 127, cc1 = s1 >> 7;
            for (int k0 = 0; k0 < 1024; k0 += 32) {
                __syncthreads();
                gload16(jA + (size_t)(m_base + r0) * 1024 + k0 + cc0 * 8, &As[s0 * 8]);
                gload16(jA + (size_t)(m_base + r1) * 1024 + k0 + cc1 * 8, &As[s1 * 8]);
                gload16(Bop + (size_t)(n_base + r0) * 1024 + k0 + cc0 * 8, &Bs[s0 * 8]);
                gload16(Bop + (size_t)(n_base + r1) * 1024 + k0 + cc1 * 8, &Bs[s1 * 8]);
                __syncthreads();
                bf16x8 af[4], bfv[4];
#pragma unroll
                for (int i = 0; i < 4; i++) {
                    af[i]  = *(const bf16x8*)&As[((q * 128) + wm + i * 16 + lm) * 8];
                    bfv[i] = *(const bf16x8*)&Bs[((q * 128) + wn + i * 16 + lm) * 8];
                }
#pragma unroll
                for (int i = 0; i < 4; i++)
#pragma unroll
                    for (int jj = 0; jj < 4; jj++)
                        acc[i][jj] = __builtin_amdgcn_mfma_f32_16x16x32_bf16(
                            af[i], bfv[jj], acc[i][jj], 0, 0, 0);
            }
#pragma unroll
            for (int i = 0; i < 4; i++) {
#pragma unroll
                for (int jj = 0; jj < 4; jj++) {
                    const int gm0 = m_base + wm + i * 16 + q * 4;
                    const int gn = n_base + wn + jj * 16 + lm;
                    float bb = b1[gn] + (b2 ? b2[gn] : 0.f);
                    if (Pd) {
                        const int g = gn >> 9, u = gn & 511;
                        const int ub2 = u >> 4, lmu = u & 15;
#pragma unroll
                        for (int r = 0; r < 4; r++) {
                            const int gm = gm0 + r;
                            const int t = gm >> 6, b = gm & 63;
                            const int tidS = (b >> 4) * 64 + ((b >> 2) & 3) * 16 + lmu;
                            size_t idx = ((((size_t)t * 32 + ub2) * 4 + (b & 3)) * 256 + tidS) * 4 + g;
                            Pd[idx] = acc[i][jj][r] + bb;
                        }
                    } else {
#pragma unroll
                        for (int r = 0; r < 4; r++)
                            Cd[(size_t)(gm0 + r) * 512 + gn] = acc[i][jj][r] + bb;
                    }
                }
            }
        }
        return;
    }

    // ================= recurrence blocks (R7 protocol) =================
    const int dir = blockIdx.y, ub = blockIdx.x, u0 = ub * 16;
    if (tid == 0) arrv = 0;

    const short* wsrc = Wpk + (size_t)(dir * 32 + ub) * 32768;
#pragma unroll
    for (int p = 0; p < 16; p++)
        gload16(wsrc + (tid + 256 * p) * 8, &Ws[(tid + 256 * p) * 8]);

    const int b0 = w * 16 + q * 4;
    const int u = u0 + lm;
    unsigned* slots = bar + dir * 32;

    float c[4];
    f32x4 xw[4];
#pragma unroll
    for (int r = 0; r < 4; r++)
        c[r] = c0p[(size_t)dir * B_ * H_ + (size_t)(b0 + r) * H_ + u];
    {
        const int t0 = dir ? (T_ - 1) : 0;
        const float* xp = XW + ((size_t)dir * T_ + t0) * (B_ * G4_) + (size_t)ub * 4096;
#pragma unroll
        for (int r = 0; r < 4; r++)
            xw[r] = *(const f32x4*)(xp + r * 1024 + tid * 4);
    }
    __syncthreads();   // Ws resident + arrv init visible

    for (int s = 0; s < T_; s++) {
        const int t = dir ? (T_ - 1 - s) : s;
        const short* Hc = Ht + ((size_t)((s & 1) * 2 + dir) << 15);

        // ---- h A-fragments, agent-scope bulk gather
        u64 hq[32];
        const short* hrow = Hc + (w * 16 + lm) * 512 + q * 8;
#pragma unroll
        for (int it = 0; it < 16; it++) {
            const u64* hp = (const u64*)(hrow + it * 32);
            hq[2 * it]     = __hip_atomic_load((u64*)hp,     __ATOMIC_RELAXED, __HIP_MEMORY_SCOPE_AGENT);
            hq[2 * it + 1] = __hip_atomic_load((u64*)hp + 1, __ATOMIC_RELAXED, __HIP_MEMORY_SCOPE_AGENT);
        }

        f32x4 acc[4];
#pragma unroll
        for (int g = 0; g < 4; g++)
#pragma unroll
            for (int r = 0; r < 4; r++) acc[g][r] = 0.f;

#pragma unroll
        for (int it = 0; it < 16; it++) {
            union { u64 q2[2]; bf16x8 v; } ua;
            ua.q2[0] = hq[2 * it]; ua.q2[1] = hq[2 * it + 1];
#pragma unroll
            for (int g = 0; g < 4; g++) {
                bf16x8 bv = *(const bf16x8*)&Ws[((g * 16 + it) * 64 + lane) * 8];
                acc[g] = __builtin_amdgcn_mfma_f32_16x16x32_bf16(ua.v, bv, acc[g], 0, 0, 0);
            }
        }

        // ---- gates; h -> LDS transpose tile (wave-private rows)
#pragma unroll
        for (int r = 0; r < 4; r++) {
            float gi = acc[0][r] + xw[r][0];
            float gf = acc[1][r] + xw[r][1];
            float gg = acc[2][r] + xw[r][2];
            float go = acc[3][r] + xw[r][3];
            float cc = fsig(gf) * c[r] + fsig(gi) * ftanh(gg);
            c[r] = cc;
            Tb[(b0 + r) * 24 + lm] = f2b(fsig(go) * ftanh(cc));
        }
        __asm__ volatile("" ::: "memory");   // order Tb writes before Tb read

        // ---- publish (u64/thread); (Y agent if helpers); own drain; arrive
        const int b = tid >> 2, qd = tid & 3;
        u64 v0 = *(const u64a*)&Tb[b * 24 + qd * 4];
        u64* ydst = Y ? (u64*)(Y + ((size_t)t * B_ + b) * (2 * H_) + dir * H_ + u0 + qd * 4)
                      : nullptr;
        {
            short* Hn = Ht + ((size_t)(((s + 1) & 1) * 2 + dir) << 15);
            __hip_atomic_store((u64*)(Hn + b * 512 + u0 + qd * 4), v0,
                               __ATOMIC_RELAXED, __HIP_MEMORY_SCOPE_AGENT);
        }
        if (ydst && job)
            __hip_atomic_store(ydst, v0, __ATOMIC_RELAXED, __HIP_MEMORY_SCOPE_AGENT);
        __asm__ volatile("s_waitcnt vmcnt(0)" ::: "memory");
        if (lane == 0)
            __hip_atomic_fetch_add(&arrv, 1u, __ATOMIC_RELAXED,
                                   __HIP_MEMORY_SCOPE_WORKGROUP);

        const unsigned tgt = (unsigned)(phase * T_ + s + 1);
        if (w == 0) {
            const unsigned a4 = 4u * (unsigned)(s + 1);
            while (__hip_atomic_load(&arrv, __ATOMIC_RELAXED,
                                     __HIP_MEMORY_SCOPE_WORKGROUP) < a4) {}
            if (lane == 0)
                __hip_atomic_store(&slots[ub], tgt,
                                   __ATOMIC_RELAXED, __HIP_MEMORY_SCOPE_AGENT);
        }

        // ---- (Y plain if no helpers) + next-step XW prefetch
        if (ydst && !job) *(u64a*)ydst = v0;
        if (s < T_ - 1) {
            const int tn = dir ? (T_ - 2 - s) : (s + 1);
            const float* xp = XW + ((size_t)dir * T_ + tn) * (B_ * G4_) + (size_t)ub * 4096;
#pragma unroll
            for (int r = 0; r < 4; r++)
                xw[r] = *(const f32x4*)(xp + r * 1024 + tid * 4);

            if (w == 0) {
                unsigned v;
                for (;;) {
                    v = (lane < 32)
                        ? __hip_atomic_load(&slots[lane], __ATOMIC_RELAXED, __HIP_MEMORY_SCOPE_AGENT)
                        : tgt;
                    if (__all(v >= tgt)) break;
                    __builtin_amdgcn_s_sleep(1);
                }
            }
            __syncthreads();
        }
    }
}

// ---------------------------------------------------------------------------
// fp32 GEMM for tiny attention matmuls (bounds-checked), act 0/1/2
// ---------------------------------------------------------------------------
__global__ __launch_bounds__(256) void gemm_bt(
    const float* __restrict__ A, const float* __restrict__ Bm,
    float* __restrict__ C, int M, int N, int K,
    const float* __restrict__ bias1, int act)
{
    __shared__ float As[16][68];
    __shared__ float Bs[16][68];
    const int tid = threadIdx.x;
    const int m_base = blockIdx.y * 64;
    const int n_base = blockIdx.x * 64;
    const int tm = tid >> 4, tn = tid & 15;
    float acc[4][4] = {};

    for (int k0 = 0; k0 < K; k0 += 16) {
#pragma unroll
        for (int i = 0; i < 4; i++) {
            int idx = tid * 4 + i;
            int r = idx >> 4, kk = idx & 15;
            int gm = m_base + r, gk = k0 + kk;
            As[kk][r] = (gm < M && gk < K) ? A[(size_t)gm * K + gk] : 0.f;
            int gn = n_base + r;
            Bs[kk][r] = (gn < N && gk < K) ? Bm[(size_t)gn * K + gk] : 0.f;
        }
        __syncthreads();
#pragma unroll
        for (int kk = 0; kk < 16; kk++) {
            float4 av = *(const float4*)&As[kk][tm * 4];
            float4 bv = *(const float4*)&Bs[kk][tn * 4];
            float a[4] = {av.x, av.y, av.z, av.w};
            float b[4] = {bv.x, bv.y, bv.z, bv.w};
#pragma unroll
            for (int i = 0; i < 4; i++)
#pragma unroll
                for (int j = 0; j < 4; j++)
                    acc[i][j] = fmaf(a[i], b[j], acc[i][j]);
        }
        __syncthreads();
    }
#pragma unroll
    for (int i = 0; i < 4; i++) {
        int gm = m_base + tm * 4 + i;
        if (gm >= M) continue;
#pragma unroll
        for (int j = 0; j < 4; j++) {
            int gn = n_base + tn * 4 + j;
            if (gn >= N) continue;
            float v = acc[i][j];
            if (bias1) v += bias1[gn];
            if (act == 1) v = tanhf(v);
            else if (act == 2) v = expf(v);
            C[(size_t)gm * N + gn] = v;
        }
    }
}

// ---------------------------------------------------------------------------
__global__ __launch_bounds__(256) void conv_f2b(
    const float* __restrict__ src, short* __restrict__ dst, int n)
{
    int i = blockIdx.x * 256 + threadIdx.x;
    if (i < n) dst[i] = f2b(src[i]);
}
__global__ __launch_bounds__(256) void conv_f2b_pad(
    const float* __restrict__ src, short* __restrict__ dst,
    int rows, int kin, int kp)
{
    int i = blockIdx.x * 256 + threadIdx.x;
    if (i < rows * kp) {
        int r = i / kp, k = i % kp;
        dst[i] = (k < kin) ? f2b(src[(size_t)r * kin + k]) : (short)0;
    }
}

__global__ __launch_bounds__(256) void attn_alpha(
    const float* __restrict__ E, float* __restrict__ AB)
{
    const int b = blockIdx.x, tid = threadIdx.x;
    __shared__ float red[256];
    __shared__ float adj[152];
    float v = 0.f;
    if (tid < 150) {
        int d = tid / F_, j = tid % F_;
        v = E[((size_t)d * B_ + b) * F_ + j];
    }
    red[tid] = v; __syncthreads();
    for (int s2 = 128; s2 > 0; s2 >>= 1) {
        if (tid < s2) red[tid] += red[tid + s2];
        __syncthreads();
    }
    float total = red[0]; __syncthreads();
    float alpha = v / total;
    float m = (tid < 150 && alpha >= 0.1f) ? 1.f : 0.f;
    red[tid] = m; __syncthreads();
    for (int s2 = 128; s2 > 0; s2 >>= 1) {
        if (tid < s2) red[tid] += red[tid + s2];
        __syncthreads();
    }
    float cnt = red[0]; __syncthreads();
    red[tid] = m * alpha; __syncthreads();
    for (int s2 = 128; s2 > 0; s2 >>= 1) {
        if (tid < s2) red[tid] += red[tid + s2];
        __syncthreads();
    }
    float selsum = red[0]; __syncthreads();
    float selmean = selsum / fmaxf(cnt, 1.f);
    if (tid < 150) adj[tid] = (m > 0.f) ? selmean : alpha;
    __syncthreads();
    if (tid < F_) AB[(size_t)b * F_ + tid] = 0.5f * (adj[tid] + adj[F_ + tid]);
}

__global__ __launch_bounds__(256) void scale_xb(
    const float* __restrict__ x, const float* __restrict__ AB,
    short* __restrict__ xb)
{
    int i = blockIdx.x * 256 + threadIdx.x;
    if (i < TB_ * KP_) {
        int r = i >> 7, k = i & 127;
        if (k < F_) {
            int b = r % B_;
            xb[i] = f2b(x[(size_t)r * F_ + k] * AB[(size_t)b * F_ + k]);
        } else xb[i] = 0;
    }
}

// ---------------------------------------------------------------------------
extern "C" void kernel_launch(void* const* d_in, const int* in_sizes, int n_in,
                              void* d_out, int out_size, void* d_ws, size_t ws_size,
                              hipStream_t stream)
{
    (void)in_sizes; (void)n_in; (void)out_size;
    const float* x       = (const float*)d_in[0];
    const float* h0      = (const float*)d_in[1];
    const float* c0      = (const float*)d_in[2];
    const float* sa_Wih  = (const float*)d_in[3];
    const float* sa_Whh  = (const float*)d_in[4];
    const float* sa_bih  = (const float*)d_in[5];
    const float* sa_bhh  = (const float*)d_in[6];
    const float* m0_Wih  = (const float*)d_in[7];
    const float* m0_Whh  = (const float*)d_in[8];
    const float* m0_bih  = (const float*)d_in[9];
    const float* m0_bhh  = (const float*)d_in[10];
    const float* mL_Wih  = (const float*)d_in[11];
    const float* mL_Whh  = (const float*)d_in[12];
    const float* mL_bih  = (const float*)d_in[13];
    const float* mL_bhh  = (const float*)d_in[14];
    const float* safc1_W = (const float*)d_in[15];
    const float* safc1_b = (const float*)d_in[16];
    const float* safc2_W = (const float*)d_in[17];
    const float* safc2_b = (const float*)d_in[18];
    const float* fc1_W   = (const float*)d_in[19];
    const float* fc1_b   = (const float*)d_in[20];

    char* cur = (char*)d_ws;
    auto alloc = [&](size_t bytes) {
        char* p = cur; cur += (bytes + 255) & ~(size_t)255; return p;
    };
    auto cv = [&](const float* s, short* d, int n) {
        conv_f2b<<<(n + 255) / 256, 256, 0, stream>>>(s, d, n);
    };

    const bool OV = ws_size >= 370000000ull;   // overlap path needs ~360 MB

    if (OV) {
        // =========== overlap path ===========
        float*    XWa  = (float*)alloc((size_t)2 * TB_ * G4_ * 4);
        float*    XWb  = (float*)alloc((size_t)2 * TB_ * G4_ * 4);
        float*    T1b  = (float*)alloc(2 * B_ * H_ * 4);
        float*    Eb   = (float*)alloc(2 * B_ * F_ * 4);
        float*    AB   = (float*)alloc(B_ * F_ * 4);
        float*    saHf = (float*)alloc(2 * B_ * H_ * 4);
        short*    xb   = (short*)alloc((size_t)TB_ * KP_ * 2);
        short*    Y0b  = (short*)alloc((size_t)TB_ * 2 * H_ * 2);
        short*    Y1b  = (short*)alloc((size_t)TB_ * 2 * H_ * 2);
        short*    Y2b  = (short*)alloc((size_t)TB_ * 2 * H_ * 2);
        short*    HtA  = (short*)alloc((size_t)2 * 2 * B_ * H_ * 2);
        short*    HtB  = (short*)alloc((size_t)2 * 2 * B_ * H_ * 2);
        short*    HtC  = (short*)alloc((size_t)2 * 2 * B_ * H_ * 2);
        short*    HtD  = (short*)alloc((size_t)2 * 2 * B_ * H_ * 2);
        const size_t PK = (size_t)2 * G4_ * H_;
        short*    Wpk4 = (short*)alloc(4 * PK * 2);
        short*    WihbSA = (short*)alloc((size_t)2 * G4_ * KP_ * 2);
        short*    WihbM0 = (short*)alloc((size_t)2 * G4_ * KP_ * 2);
        short*    WihbL  = (short*)alloc((size_t)2 * 2 * G4_ * 2 * H_ * 2);
        short*    fc1b   = (short*)alloc((size_t)H_ * 2 * H_ * 2);
        unsigned* bar    = (unsigned*)alloc(1024);

        auto g16 = [&](const short* Ap, const short* Bp, float* Pp,
                       int K, const float* b1, const float* b2) {
            gemm_bf16<<<dim3(G4_ / 128, TB_ / 128), 256, 0, stream>>>(
                Ap, Bp, nullptr, Pp, TB_, G4_, K, b1, b2);
        };
        auto lstm = [&](const float* XWp, const short* Wp, short* Htp,
                        const float* c0p, short* Yp, int pidx,
                        const short* ja, const short* jb, float* jp, float* jc,
                        const float* b1, const float* b2, int job) {
            lstm_phase<<<dim3(job ? 96 : 32, 2), 256, 0, stream>>>(
                XWp, Wp, Htp, c0p, Yp, bar, pidx, ja, jb, jp, jc, b1, b2, job);
        };

        // ---- hoisted prep (off the inter-phase critical path) ----
        prep_init<<<256, 256, 0, stream>>>(h0, HtA, HtB, HtC, HtD, bar);
        cv(fc1_W, fc1b, H_ * 2 * H_);
        conv_f2b_pad<<<(2 * G4_ * KP_ + 255) / 256, 256, 0, stream>>>(sa_Wih, WihbSA, 2 * G4_, F_, KP_);
        conv_f2b_pad<<<(2 * G4_ * KP_ + 255) / 256, 256, 0, stream>>>(m0_Wih, WihbM0, 2 * G4_, F_, KP_);
        cv(mL_Wih, WihbL, 2 * 2 * G4_ * 2 * H_);
        pack_whh<<<(2 * G4_ * H_ + 255) / 256, 256, 0, stream>>>(sa_Whh, Wpk4);
        pack_whh<<<(2 * G4_ * H_ + 255) / 256, 256, 0, stream>>>(m0_Whh, Wpk4 + PK);
        pack_whh<<<(2 * G4_ * H_ + 255) / 256, 256, 0, stream>>>(mL_Whh, Wpk4 + 2 * PK);
        pack_whh<<<(2 * G4_ * H_ + 255) / 256, 256, 0, stream>>>(mL_Whh + (size_t)2 * G4_ * H_, Wpk4 + 3 * PK);
        conv_f2b_pad<<<(TB_ * KP_ + 255) / 256, 256, 0, stream>>>(x, xb, TB_, F_, KP_);

        // ---- Phase A ----
        for (int d = 0; d < 2; d++)
            g16(xb, WihbSA + (size_t)d * G4_ * KP_, XWa + (size_t)d * TB_ * G4_,
                KP_, sa_bih + d * G4_, sa_bhh + d * G4_);
        lstm(XWa, Wpk4, HtA, c0, nullptr, 0,
             nullptr, nullptr, nullptr, nullptr, nullptr, nullptr, 0);
        ht_to_f32<<<256, 256, 0, stream>>>(HtA, saHf);
        gemm_bt<<<dim3(8, 2), 256, 0, stream>>>(saHf, safc1_W, T1b, 2 * B_, H_, H_, safc1_b, 1);
        gemm_bt<<<dim3(2, 2), 256, 0, stream>>>(T1b, safc2_W, Eb, 2 * B_, F_, H_, safc2_b, 2);
        attn_alpha<<<B_, 256, 0, stream>>>(Eb, AB);
        scale_xb<<<(TB_ * KP_ + 255) / 256, 256, 0, stream>>>(x, AB, xb);

        // ---- Phase B (helpers build XW_C into XWb from Y0b) ----
        for (int d = 0; d < 2; d++)
            g16(xb, WihbM0 + (size_t)d * G4_ * KP_, XWa + (size_t)d * TB_ * G4_,
                KP_, m0_bih + d * G4_, m0_bhh + d * G4_);
        lstm(XWa, Wpk4 + PK, HtB, c0, Y0b, 1,
             Y0b, WihbL, XWb, nullptr, mL_bih, mL_bhh, 1);

        // ---- Phase C (helpers build XW_D into XWa from Y1b) ----
        lstm(XWb, Wpk4 + 2 * PK, HtC, c0 + 2 * B_ * H_, Y1b, 2,
             Y1b, WihbL + (size_t)2 * G4_ * 2 * H_, XWa, nullptr,
             mL_bih + 2 * G4_, mL_bhh + 2 * G4_, 1);

        // ---- Phase D (helpers compute FC1 -> d_out from Y2b) ----
        lstm(XWa, Wpk4 + 3 * PK, HtD, c0 + 4 * B_ * H_, Y2b, 3,
             Y2b, fc1b, nullptr, (float*)d_out, fc1_b, nullptr, 2);
        return;
    }

    // =========== fallback: R7 serial path (proven 4145us) ===========
    float*    XW   = (float*)alloc((size_t)2 * TB_ * G4_ * 4);
    float*    T1b  = (float*)alloc(2 * B_ * H_ * 4);
    float*    Eb   = (float*)alloc(2 * B_ * F_ * 4);
    float*    AB   = (float*)alloc(B_ * F_ * 4);
    float*    saHf = (float*)alloc(2 * B_ * H_ * 4);
    short*    xb   = (short*)alloc((size_t)TB_ * KP_ * 2);
    short*    Y0b  = (short*)alloc((size_t)TB_ * 2 * H_ * 2);
    short*    Y1b  = (short*)alloc((size_t)TB_ * 2 * H_ * 2);
    short*    Ht   = (short*)alloc((size_t)2 * 2 * B_ * H_ * 2);
    short*    Wpk  = (short*)alloc((size_t)2 * G4_ * H_ * 2);
    short*    Wihb = (short*)alloc((size_t)2 * G4_ * KP_ * 2);
    short*    WihbL= (short*)alloc((size_t)2 * G4_ * 2 * H_ * 2);
    short*    fc1b = (short*)alloc((size_t)H_ * 2 * H_ * 2);
    unsigned* bar  = (unsigned*)alloc(1024);

    auto g16f = [&](const short* Ap, const short* Bp, float* Cp, float* Pp,
                    int M, int N, int K, const float* b1, const float* b2) {
        gemm_bf16<<<dim3(N / 128, M / 128), 256, 0, stream>>>(Ap, Bp, Cp, Pp, M, N, K, b1, b2);
    };
    auto phase = [&](const float* Whh_p, const float* h0p, const float* c0p,
                     short* Yout, int pidx) {
        pack_whh<<<(2 * G4_ * H_ + 255) / 256, 256, 0, stream>>>(Whh_p, Wpk);
        init_phase<<<256, 256, 0, stream>>>(h0p, Ht, bar, pidx == 0 ? 1 : 0);
        lstm_phase<<<dim3(32, 2), 256, 0, stream>>>(XW, Wpk, Ht, c0p, Yout, bar, pidx,
            nullptr, nullptr, nullptr, nullptr, nullptr, nullptr, 0);
    };

    cv(fc1_W, fc1b, H_ * 2 * H_);
    conv_f2b_pad<<<(TB_ * KP_ + 255) / 256, 256, 0, stream>>>(x, xb, TB_, F_, KP_);
    conv_f2b_pad<<<(2 * G4_ * KP_ + 255) / 256, 256, 0, stream>>>(sa_Wih, Wihb, 2 * G4_, F_, KP_);
    for (int d = 0; d < 2; d++)
        g16f(xb, Wihb + (size_t)d * G4_ * KP_, nullptr, XW + (size_t)d * TB_ * G4_,
             TB_, G4_, KP_, sa_bih + d * G4_, sa_bhh + d * G4_);
    phase(sa_Whh, h0, c0, nullptr, 0);
    ht_to_f32<<<256, 256, 0, stream>>>(Ht, saHf);
    gemm_bt<<<dim3(8, 2), 256, 0, stream>>>(saHf, safc1_W, T1b, 2 * B_, H_, H_, safc1_b, 1);
    gemm_bt<<<dim3(2, 2), 256, 0, stream>>>(T1b, safc2_W, Eb, 2 * B_, F_, H_, safc2_b, 2);
    attn_alpha<<<B_, 256, 0, stream>>>(Eb, AB);
    scale_xb<<<(TB_ * KP_ + 255) / 256, 256, 0, stream>>>(x, AB, xb);

    conv_f2b_pad<<<(2 * G4_ * KP_ + 255) / 256, 256, 0, stream>>>(m0_Wih, Wihb, 2 * G4_, F_, KP_);
    for (int d = 0; d < 2; d++)
        g16f(xb, Wihb + (size_t)d * G4_ * KP_, nullptr, XW + (size_t)d * TB_ * G4_,
             TB_, G4_, KP_, m0_bih + d * G4_, m0_bhh + d * G4_);
    phase(m0_Whh, h0, c0, Y0b, 1);

    cv(mL_Wih, WihbL, 2 * G4_ * 2 * H_);
    for (int d = 0; d < 2; d++)
        g16f(Y0b, WihbL + (size_t)d * G4_ * 2 * H_, nullptr, XW + (size_t)d * TB_ * G4_,
             TB_, G4_, 2 * H_, mL_bih + d * G4_, mL_bhh + d * G4_);
    phase(mL_Whh, h0 + 2 * B_ * H_, c0 + 2 * B_ * H_, Y1b, 2);

    cv(mL_Wih + (size_t)2 * G4_ * 2 * H_, WihbL, 2 * G4_ * 2 * H_);
    for (int d = 0; d < 2; d++)
        g16f(Y1b, WihbL + (size_t)d * G4_ * 2 * H_, nullptr, XW + (size_t)d * TB_ * G4_,
             TB_, G4_, 2 * H_, mL_bih + (2 + d) * G4_, mL_bhh + (2 + d) * G4_);
    phase(mL_Whh + (size_t)2 * G4_ * H_, h0 + 4 * B_ * H_, c0 + 4 * B_ * H_, Y0b, 3);

    g16f(Y0b, fc1b, (float*)d_out, nullptr, TB_, H_, 2 * H_, fc1_b, nullptr);
}

// Round 9
// 4041.596 us; speedup vs baseline: 1.3447x; 1.0253x over previous
//
#include <hip/hip_runtime.h>
#include <cstddef>

#define T_  128
#define B_  64
#define F_  75
#define H_  512
#define G4_ 2048
#define TB_ (T_ * B_)
#define KP_ 128   // padded K for F=75 inputs

typedef __bf16 bf16x8 __attribute__((ext_vector_type(8)));
typedef float  f32x4  __attribute__((ext_vector_type(4)));
typedef unsigned long long u64;
typedef unsigned long long __attribute__((may_alias)) u64a;

__device__ __forceinline__ short f2b(float x) {
    union { float f; unsigned u; } v; v.f = x;
    return (short)((v.u + 0x7fffu + ((v.u >> 16) & 1u)) >> 16);
}
__device__ __forceinline__ float b2f(short s) {
    union { float f; unsigned u; } v; v.u = ((unsigned)(unsigned short)s) << 16;
    return v.f;
}
__device__ __forceinline__ void gload16(const void* g, void* l) {
    __builtin_amdgcn_global_load_lds(
        (const __attribute__((address_space(1))) void*)g,
        (__attribute__((address_space(3))) void*)l, 16, 0, 0);
}
__device__ __forceinline__ float fsig(float x) {
    return __builtin_amdgcn_rcpf(1.f + __expf(-x));
}
__device__ __forceinline__ float ftanh(float x) {
    return 1.f - 2.f * __builtin_amdgcn_rcpf(1.f + __expf(2.f * x));
}
// unpack 4 packed bf16 (one u64) -> f32x4
__device__ __forceinline__ f32x4 xw4(const short* xp) {
    u64 v = *(const u64a*)xp;
    f32x4 o;
    o[0] = b2f((short)(v & 0xFFFFu));
    o[1] = b2f((short)((v >> 16) & 0xFFFFu));
    o[2] = b2f((short)((v >> 32) & 0xFFFFu));
    o[3] = b2f((short)(v >> 48));
    return o;
}

// ---------------------------------------------------------------------------
// bf16 MFMA GEMM. If P != null: write BF16 results into the step-kernel's
// packed XW layout  P[t][ub(32)][r(4)][tidS(256)][g(4)]  (biases included).
// Else: C(M,N) fp32 row-major.
// ---------------------------------------------------------------------------
__global__ __launch_bounds__(256) void gemm_bf16(
    const short* __restrict__ A, const short* __restrict__ Bm,
    float* __restrict__ C, short* __restrict__ P, int M, int N, int K,
    const float* __restrict__ bias1, const float* __restrict__ bias2)
{
    __shared__ short As[4096];
    __shared__ short Bs[4096];
    const int tid = threadIdx.x;
    const int m_base = blockIdx.y * 128;
    const int n_base = blockIdx.x * 128;
    const int w = tid >> 6, lane = tid & 63;
    const int wm = (w >> 1) * 64, wn = (w & 1) * 64;
    const int lm = lane & 15, q = lane >> 4;

    f32x4 acc[4][4];
#pragma unroll
    for (int i = 0; i < 4; i++)
#pragma unroll
        for (int j = 0; j < 4; j++)
#pragma unroll
            for (int r = 0; r < 4; r++) acc[i][j][r] = 0.f;

    const int s0 = tid, s1 = tid + 256;
    const int r0 = s0 & 127, c0 = s0 >> 7;
    const int r1 = s1 & 127, c1 = s1 >> 7;

    for (int k0 = 0; k0 < K; k0 += 32) {
        __syncthreads();
        gload16(A + (size_t)(m_base + r0) * K + k0 + c0 * 8, &As[s0 * 8]);
        gload16(A + (size_t)(m_base + r1) * K + k0 + c1 * 8, &As[s1 * 8]);
        gload16(Bm + (size_t)(n_base + r0) * K + k0 + c0 * 8, &Bs[s0 * 8]);
        gload16(Bm + (size_t)(n_base + r1) * K + k0 + c1 * 8, &Bs[s1 * 8]);
        __syncthreads();
        bf16x8 af[4], bfv[4];
#pragma unroll
        for (int i = 0; i < 4; i++) {
            af[i]  = *(const bf16x8*)&As[((q * 128) + wm + i * 16 + lm) * 8];
            bfv[i] = *(const bf16x8*)&Bs[((q * 128) + wn + i * 16 + lm) * 8];
        }
#pragma unroll
        for (int i = 0; i < 4; i++)
#pragma unroll
            for (int j = 0; j < 4; j++)
                acc[i][j] = __builtin_amdgcn_mfma_f32_16x16x32_bf16(
                    af[i], bfv[j], acc[i][j], 0, 0, 0);
    }

#pragma unroll
    for (int i = 0; i < 4; i++) {
#pragma unroll
        for (int j = 0; j < 4; j++) {
            const int gm0 = m_base + wm + i * 16 + q * 4;
            const int gn = n_base + wn + j * 16 + lm;
            float bb = (bias1 ? bias1[gn] : 0.f) + (bias2 ? bias2[gn] : 0.f);
            if (P) {
                const int g = gn >> 9, u = gn & 511;
                const int ub = u >> 4, lmu = u & 15;
#pragma unroll
                for (int r = 0; r < 4; r++) {
                    const int gm = gm0 + r;
                    const int t = gm >> 6, b = gm & 63;
                    const int tidS = (b >> 4) * 64 + ((b >> 2) & 3) * 16 + lmu;
                    size_t idx = ((((size_t)t * 32 + ub) * 4 + (b & 3)) * 256 + tidS) * 4 + g;
                    P[idx] = f2b(acc[i][j][r] + bb);
                }
            } else {
#pragma unroll
                for (int r = 0; r < 4; r++)
                    C[(size_t)(gm0 + r) * N + gn] = acc[i][j][r] + bb;
            }
        }
    }
}

// ---------------------------------------------------------------------------
// Pack Whh (2,4H,H) fp32 -> bf16 B-fragments:
// Wpk[dir][ub(32)][g(4)][it(16)][lane(64)][8]
// ---------------------------------------------------------------------------
__global__ __launch_bounds__(256) void pack_whh(
    const float* __restrict__ W, short* __restrict__ Wpk)
{
    int i = blockIdx.x * 256 + threadIdx.x;
    if (i >= 2 * G4_ * H_) return;
    int e = i & 7, lane = (i >> 3) & 63, it = (i >> 9) & 15;
    int g = (i >> 13) & 3, ub = (i >> 15) & 31, dir = (i >> 20) & 1;
    int lm = lane & 15, qq = lane >> 4;
    float v = W[((size_t)dir * G4_ + g * H_ + ub * 16 + lm) * H_
                + it * 32 + qq * 8 + e];
    Wpk[i] = f2b(v);
}

// ---------------------------------------------------------------------------
// bar layout (u32): [0..63] per-BLOCK step tags: dir*32 + ub. Tags monotonic
// across phases within one launch; zeroed at launch start.
// ---------------------------------------------------------------------------
__global__ __launch_bounds__(256) void init_phase(
    const float* __restrict__ h0s, short* __restrict__ Ht,
    unsigned* __restrict__ bar, int zero_bar)
{
    int i = blockIdx.x * 256 + threadIdx.x;
    if (i < 2 * B_ * H_) Ht[i] = f2b(h0s[i]);
    if (zero_bar && i < 64) bar[i] = 0;
}

// overlap path: init ALL phase Ht buffers + bar in one dispatch
__global__ __launch_bounds__(256) void prep_init(
    const float* __restrict__ h0, short* __restrict__ HtA,
    short* __restrict__ HtB, short* __restrict__ HtC, short* __restrict__ HtD,
    unsigned* __restrict__ bar)
{
    int i = blockIdx.x * 256 + threadIdx.x;
    if (i < 2 * B_ * H_) {
        short vA = f2b(h0[i]);
        HtA[i] = vA;
        HtB[i] = vA;
        HtC[i] = f2b(h0[2 * B_ * H_ + i]);
        HtD[i] = f2b(h0[4 * B_ * H_ + i]);
    }
    if (i < 64) bar[i] = 0;
}

__global__ __launch_bounds__(256) void ht_to_f32(
    const short* __restrict__ Ht0, float* __restrict__ out)
{
    int i = blockIdx.x * 256 + threadIdx.x;
    if (i < 2 * B_ * H_) out[i] = b2f(Ht0[i]);
}

// ---------------------------------------------------------------------------
// Persistent phase kernel (R7 protocol, 750us/phase measured) + optional
// HELPER blocks (blockIdx.x >= 32) that overlap the NEXT phase's K=1024
// GEMM with this phase's recurrence, consuming Y per-timestep via the tag
// line.  job: 0 = none, 1 = packed-XW GEMM (bf16, per-dir), 2 = FC1 -> C.
// Y stores are agent-scope BEFORE the drain when job!=0 (tag certifies Y).
// ---------------------------------------------------------------------------
__global__ __launch_bounds__(256, 1) void lstm_phase(
    const short* __restrict__ XW,   // packed (2,T,32,4,256,4) bf16
    const short* __restrict__ Wpk,  // packed Whh bf16
    short* __restrict__ Ht,         // (2buf,2dir,64b,512u) bf16
    const float* __restrict__ c0p,  // (2,B,H) fp32 initial c
    short* __restrict__ Y,          // (T,B,2H) bf16 or null
    unsigned* __restrict__ bar, int phase,
    const short* __restrict__ jA, const short* __restrict__ jB,
    short* __restrict__ jP, float* __restrict__ jC,
    const float* __restrict__ jb1, const float* __restrict__ jb2, int job)
{
    __shared__ short Ws[32768];     // rec: 64KB weights | helper: As/Bs union
    __shared__ short Tb[64 * 24];
    __shared__ unsigned arrv;
    const int tid = threadIdx.x, w = tid >> 6, lane = tid & 63;
    const int lm = lane & 15, q = lane >> 4;

    if (blockIdx.x >= 32) {
        // ================= helper blocks =================
        if (job == 0) return;
        short* As = Ws;
        short* Bs = Ws + 4096;
        const int hh = blockIdx.x - 32;          // 0..63
        const int dirh = blockIdx.y;
        const unsigned pT = (unsigned)(phase * T_);
        const int wm = (w >> 1) * 64, wn = (w & 1) * 64;

        const short* Bop; short* Pd; float* Cd; const float* b1; const float* b2;
        int n_tile, grp, iters, stride;
        if (job == 1) {
            Bop = jB + (size_t)dirh * G4_ * 1024;
            Pd = jP + (size_t)dirh * TB_ * G4_;
            Cd = nullptr;
            b1 = jb1 + dirh * G4_; b2 = jb2 + dirh * G4_;
            n_tile = hh & 15; grp = hh >> 4; iters = 16; stride = 4;
        } else {
            Bop = jB; Pd = nullptr; Cd = jC; b1 = jb1; b2 = nullptr;
            int H2 = dirh * 64 + hh;             // 0..127
            n_tile = H2 & 3; grp = H2 >> 2; iters = 2; stride = 32;
        }
        const int n_base = n_tile * 128;

        for (int it2 = 0; it2 < iters; it2++) {
            int j = grp + stride * it2;
            int k = (j & 1) ? 32 + (j >> 1) : 31 - (j >> 1);   // center-out
            int m_base = k * 128, t0 = 2 * k;
            // readiness: dir0 tags >= pT+t0+2, dir1 tags >= pT+T-t0
            if (w == 0) {
                unsigned tgt = (lane < 32) ? pT + (unsigned)(t0 + 2)
                                           : pT + (unsigned)(T_ - t0);
                int itc = 0;
                for (;;) {
                    unsigned v = __hip_atomic_load(&bar[lane], __ATOMIC_RELAXED,
                                                   __HIP_MEMORY_SCOPE_AGENT);
                    if (__all(v >= tgt)) break;
                    if (++itc > (1 << 19)) break;   // failsafe vs deadlock
                    __builtin_amdgcn_s_sleep(32);
                }
            }
            __syncthreads();

            f32x4 acc[4][4];
#pragma unroll
            for (int i = 0; i < 4; i++)
#pragma unroll
                for (int jj = 0; jj < 4; jj++)
#pragma unroll
                    for (int r = 0; r < 4; r++) acc[i][jj][r] = 0.f;

            const int s0 = tid, s1 = tid + 256;
            const int r0 = s0 & 127, cc0 = s0 >> 7;
            const int r1 = s1 & 127, cc1 = s1 >> 7;
            for (int k0 = 0; k0 < 1024; k0 += 32) {
                __syncthreads();
                gload16(jA + (size_t)(m_base + r0) * 1024 + k0 + cc0 * 8, &As[s0 * 8]);
                gload16(jA + (size_t)(m_base + r1) * 1024 + k0 + cc1 * 8, &As[s1 * 8]);
                gload16(Bop + (size_t)(n_base + r0) * 1024 + k0 + cc0 * 8, &Bs[s0 * 8]);
                gload16(Bop + (size_t)(n_base + r1) * 1024 + k0 + cc1 * 8, &Bs[s1 * 8]);
                __syncthreads();
                bf16x8 af[4], bfv[4];
#pragma unroll
                for (int i = 0; i < 4; i++) {
                    af[i]  = *(const bf16x8*)&As[((q * 128) + wm + i * 16 + lm) * 8];
                    bfv[i] = *(const bf16x8*)&Bs[((q * 128) + wn + i * 16 + lm) * 8];
                }
#pragma unroll
                for (int i = 0; i < 4; i++)
#pragma unroll
                    for (int jj = 0; jj < 4; jj++)
                        acc[i][jj] = __builtin_amdgcn_mfma_f32_16x16x32_bf16(
                            af[i], bfv[jj], acc[i][jj], 0, 0, 0);
            }
#pragma unroll
            for (int i = 0; i < 4; i++) {
#pragma unroll
                for (int jj = 0; jj < 4; jj++) {
                    const int gm0 = m_base + wm + i * 16 + q * 4;
                    const int gn = n_base + wn + jj * 16 + lm;
                    float bb = b1[gn] + (b2 ? b2[gn] : 0.f);
                    if (Pd) {
                        const int g = gn >> 9, u = gn & 511;
                        const int ub2 = u >> 4, lmu = u & 15;
#pragma unroll
                        for (int r = 0; r < 4; r++) {
                            const int gm = gm0 + r;
                            const int t = gm >> 6, b = gm & 63;
                            const int tidS = (b >> 4) * 64 + ((b >> 2) & 3) * 16 + lmu;
                            size_t idx = ((((size_t)t * 32 + ub2) * 4 + (b & 3)) * 256 + tidS) * 4 + g;
                            Pd[idx] = f2b(acc[i][jj][r] + bb);
                        }
                    } else {
#pragma unroll
                        for (int r = 0; r < 4; r++)
                            Cd[(size_t)(gm0 + r) * 512 + gn] = acc[i][jj][r] + bb;
                    }
                }
            }
        }
        return;
    }

    // ================= recurrence blocks (R7 protocol) =================
    const int dir = blockIdx.y, ub = blockIdx.x, u0 = ub * 16;
    if (tid == 0) arrv = 0;

    const short* wsrc = Wpk + (size_t)(dir * 32 + ub) * 32768;
#pragma unroll
    for (int p = 0; p < 16; p++)
        gload16(wsrc + (tid + 256 * p) * 8, &Ws[(tid + 256 * p) * 8]);

    const int b0 = w * 16 + q * 4;
    const int u = u0 + lm;
    unsigned* slots = bar + dir * 32;

    float c[4];
    f32x4 xw[4];
#pragma unroll
    for (int r = 0; r < 4; r++)
        c[r] = c0p[(size_t)dir * B_ * H_ + (size_t)(b0 + r) * H_ + u];
    {
        const int t0 = dir ? (T_ - 1) : 0;
        const short* xp = XW + ((size_t)dir * T_ + t0) * (size_t)(B_ * G4_) + (size_t)ub * 4096;
#pragma unroll
        for (int r = 0; r < 4; r++)
            xw[r] = xw4(xp + r * 1024 + tid * 4);
    }
    __syncthreads();   // Ws resident + arrv init visible

    for (int s = 0; s < T_; s++) {
        const int t = dir ? (T_ - 1 - s) : s;
        const short* Hc = Ht + ((size_t)((s & 1) * 2 + dir) << 15);

        // ---- h A-fragments, agent-scope bulk gather
        u64 hq[32];
        const short* hrow = Hc + (w * 16 + lm) * 512 + q * 8;
#pragma unroll
        for (int it = 0; it < 16; it++) {
            const u64* hp = (const u64*)(hrow + it * 32);
            hq[2 * it]     = __hip_atomic_load((u64*)hp,     __ATOMIC_RELAXED, __HIP_MEMORY_SCOPE_AGENT);
            hq[2 * it + 1] = __hip_atomic_load((u64*)hp + 1, __ATOMIC_RELAXED, __HIP_MEMORY_SCOPE_AGENT);
        }

        f32x4 acc[4];
#pragma unroll
        for (int g = 0; g < 4; g++)
#pragma unroll
            for (int r = 0; r < 4; r++) acc[g][r] = 0.f;

#pragma unroll
        for (int it = 0; it < 16; it++) {
            union { u64 q2[2]; bf16x8 v; } ua;
            ua.q2[0] = hq[2 * it]; ua.q2[1] = hq[2 * it + 1];
#pragma unroll
            for (int g = 0; g < 4; g++) {
                bf16x8 bv = *(const bf16x8*)&Ws[((g * 16 + it) * 64 + lane) * 8];
                acc[g] = __builtin_amdgcn_mfma_f32_16x16x32_bf16(ua.v, bv, acc[g], 0, 0, 0);
            }
        }

        // ---- gates; h -> LDS transpose tile (wave-private rows)
#pragma unroll
        for (int r = 0; r < 4; r++) {
            float gi = acc[0][r] + xw[r][0];
            float gf = acc[1][r] + xw[r][1];
            float gg = acc[2][r] + xw[r][2];
            float go = acc[3][r] + xw[r][3];
            float cc = fsig(gf) * c[r] + fsig(gi) * ftanh(gg);
            c[r] = cc;
            Tb[(b0 + r) * 24 + lm] = f2b(fsig(go) * ftanh(cc));
        }
        __asm__ volatile("" ::: "memory");   // order Tb writes before Tb read

        // ---- publish (u64/thread); (Y agent if helpers); own drain; arrive
        const int b = tid >> 2, qd = tid & 3;
        u64 v0 = *(const u64a*)&Tb[b * 24 + qd * 4];
        u64* ydst = Y ? (u64*)(Y + ((size_t)t * B_ + b) * (2 * H_) + dir * H_ + u0 + qd * 4)
                      : nullptr;
        {
            short* Hn = Ht + ((size_t)(((s + 1) & 1) * 2 + dir) << 15);
            __hip_atomic_store((u64*)(Hn + b * 512 + u0 + qd * 4), v0,
                               __ATOMIC_RELAXED, __HIP_MEMORY_SCOPE_AGENT);
        }
        if (ydst && job)
            __hip_atomic_store(ydst, v0, __ATOMIC_RELAXED, __HIP_MEMORY_SCOPE_AGENT);
        __asm__ volatile("s_waitcnt vmcnt(0)" ::: "memory");
        if (lane == 0)
            __hip_atomic_fetch_add(&arrv, 1u, __ATOMIC_RELAXED,
                                   __HIP_MEMORY_SCOPE_WORKGROUP);

        const unsigned tgt = (unsigned)(phase * T_ + s + 1);
        if (w == 0) {
            const unsigned a4 = 4u * (unsigned)(s + 1);
            while (__hip_atomic_load(&arrv, __ATOMIC_RELAXED,
                                     __HIP_MEMORY_SCOPE_WORKGROUP) < a4) {}
            if (lane == 0)
                __hip_atomic_store(&slots[ub], tgt,
                                   __ATOMIC_RELAXED, __HIP_MEMORY_SCOPE_AGENT);
        }

        // ---- (Y plain if no helpers) + next-step XW prefetch
        if (ydst && !job) *(u64a*)ydst = v0;
        if (s < T_ - 1) {
            const int tn = dir ? (T_ - 2 - s) : (s + 1);
            const short* xp = XW + ((size_t)dir * T_ + tn) * (size_t)(B_ * G4_) + (size_t)ub * 4096;
#pragma unroll
            for (int r = 0; r < 4; r++)
                xw[r] = xw4(xp + r * 1024 + tid * 4);

            if (w == 0) {
                unsigned v;
                for (;;) {
                    v = (lane < 32)
                        ? __hip_atomic_load(&slots[lane], __ATOMIC_RELAXED, __HIP_MEMORY_SCOPE_AGENT)
                        : tgt;
                    if (__all(v >= tgt)) break;
                    __builtin_amdgcn_s_sleep(1);
                }
            }
            __syncthreads();
        }
    }
}

// ---------------------------------------------------------------------------
// fp32 GEMM for tiny attention matmuls (bounds-checked), act 0/1/2
// ---------------------------------------------------------------------------
__global__ __launch_bounds__(256) void gemm_bt(
    const float* __restrict__ A, const float* __restrict__ Bm,
    float* __restrict__ C, int M, int N, int K,
    const float* __restrict__ bias1, int act)
{
    __shared__ float As[16][68];
    __shared__ float Bs[16][68];
    const int tid = threadIdx.x;
    const int m_base = blockIdx.y * 64;
    const int n_base = blockIdx.x * 64;
    const int tm = tid >> 4, tn = tid & 15;
    float acc[4][4] = {};

    for (int k0 = 0; k0 < K; k0 += 16) {
#pragma unroll
        for (int i = 0; i < 4; i++) {
            int idx = tid * 4 + i;
            int r = idx >> 4, kk = idx & 15;
            int gm = m_base + r, gk = k0 + kk;
            As[kk][r] = (gm < M && gk < K) ? A[(size_t)gm * K + gk] : 0.f;
            int gn = n_base + r;
            Bs[kk][r] = (gn < N && gk < K) ? Bm[(size_t)gn * K + gk] : 0.f;
        }
        __syncthreads();
#pragma unroll
        for (int kk = 0; kk < 16; kk++) {
            float4 av = *(const float4*)&As[kk][tm * 4];
            float4 bv = *(const float4*)&Bs[kk][tn * 4];
            float a[4] = {av.x, av.y, av.z, av.w};
            float b[4] = {bv.x, bv.y, bv.z, bv.w};
#pragma unroll
            for (int i = 0; i < 4; i++)
#pragma unroll
                for (int j = 0; j < 4; j++)
                    acc[i][j] = fmaf(a[i], b[j], acc[i][j]);
        }
        __syncthreads();
    }
#pragma unroll
    for (int i = 0; i < 4; i++) {
        int gm = m_base + tm * 4 + i;
        if (gm >= M) continue;
#pragma unroll
        for (int j = 0; j < 4; j++) {
            int gn = n_base + tn * 4 + j;
            if (gn >= N) continue;
            float v = acc[i][j];
            if (bias1) v += bias1[gn];
            if (act == 1) v = tanhf(v);
            else if (act == 2) v = expf(v);
            C[(size_t)gm * N + gn] = v;
        }
    }
}

// ---------------------------------------------------------------------------
__global__ __launch_bounds__(256) void conv_f2b(
    const float* __restrict__ src, short* __restrict__ dst, int n)
{
    int i = blockIdx.x * 256 + threadIdx.x;
    if (i < n) dst[i] = f2b(src[i]);
}
__global__ __launch_bounds__(256) void conv_f2b_pad(
    const float* __restrict__ src, short* __restrict__ dst,
    int rows, int kin, int kp)
{
    int i = blockIdx.x * 256 + threadIdx.x;
    if (i < rows * kp) {
        int r = i / kp, k = i % kp;
        dst[i] = (k < kin) ? f2b(src[(size_t)r * kin + k]) : (short)0;
    }
}

__global__ __launch_bounds__(256) void attn_alpha(
    const float* __restrict__ E, float* __restrict__ AB)
{
    const int b = blockIdx.x, tid = threadIdx.x;
    __shared__ float red[256];
    __shared__ float adj[152];
    float v = 0.f;
    if (tid < 150) {
        int d = tid / F_, j = tid % F_;
        v = E[((size_t)d * B_ + b) * F_ + j];
    }
    red[tid] = v; __syncthreads();
    for (int s2 = 128; s2 > 0; s2 >>= 1) {
        if (tid < s2) red[tid] += red[tid + s2];
        __syncthreads();
    }
    float total = red[0]; __syncthreads();
    float alpha = v / total;
    float m = (tid < 150 && alpha >= 0.1f) ? 1.f : 0.f;
    red[tid] = m; __syncthreads();
    for (int s2 = 128; s2 > 0; s2 >>= 1) {
        if (tid < s2) red[tid] += red[tid + s2];
        __syncthreads();
    }
    float cnt = red[0]; __syncthreads();
    red[tid] = m * alpha; __syncthreads();
    for (int s2 = 128; s2 > 0; s2 >>= 1) {
        if (tid < s2) red[tid] += red[tid + s2];
        __syncthreads();
    }
    float selsum = red[0]; __syncthreads();
    float selmean = selsum / fmaxf(cnt, 1.f);
    if (tid < 150) adj[tid] = (m > 0.f) ? selmean : alpha;
    __syncthreads();
    if (tid < F_) AB[(size_t)b * F_ + tid] = 0.5f * (adj[tid] + adj[F_ + tid]);
}

__global__ __launch_bounds__(256) void scale_xb(
    const float* __restrict__ x, const float* __restrict__ AB,
    short* __restrict__ xb)
{
    int i = blockIdx.x * 256 + threadIdx.x;
    if (i < TB_ * KP_) {
        int r = i >> 7, k = i & 127;
        if (k < F_) {
            int b = r % B_;
            xb[i] = f2b(x[(size_t)r * F_ + k] * AB[(size_t)b * F_ + k]);
        } else xb[i] = 0;
    }
}

// ---------------------------------------------------------------------------
extern "C" void kernel_launch(void* const* d_in, const int* in_sizes, int n_in,
                              void* d_out, int out_size, void* d_ws, size_t ws_size,
                              hipStream_t stream)
{
    (void)in_sizes; (void)n_in; (void)out_size;
    const float* x       = (const float*)d_in[0];
    const float* h0      = (const float*)d_in[1];
    const float* c0      = (const float*)d_in[2];
    const float* sa_Wih  = (const float*)d_in[3];
    const float* sa_Whh  = (const float*)d_in[4];
    const float* sa_bih  = (const float*)d_in[5];
    const float* sa_bhh  = (const float*)d_in[6];
    const float* m0_Wih  = (const float*)d_in[7];
    const float* m0_Whh  = (const float*)d_in[8];
    const float* m0_bih  = (const float*)d_in[9];
    const float* m0_bhh  = (const float*)d_in[10];
    const float* mL_Wih  = (const float*)d_in[11];
    const float* mL_Whh  = (const float*)d_in[12];
    const float* mL_bih  = (const float*)d_in[13];
    const float* mL_bhh  = (const float*)d_in[14];
    const float* safc1_W = (const float*)d_in[15];
    const float* safc1_b = (const float*)d_in[16];
    const float* safc2_W = (const float*)d_in[17];
    const float* safc2_b = (const float*)d_in[18];
    const float* fc1_W   = (const float*)d_in[19];
    const float* fc1_b   = (const float*)d_in[20];

    char* const start = (char*)d_ws;
    char* cur = start;
    auto alloc = [&](size_t bytes) {
        char* p = cur; cur += (bytes + 255) & ~(size_t)255; return p;
    };
    auto cv = [&](const float* s, short* d, int n) {
        conv_f2b<<<(n + 255) / 256, 256, 0, stream>>>(s, d, n);
    };

    // ---------- try compact overlap layout (exact-fit runtime check) -------
    short*    XWa  = (short*)alloc((size_t)2 * TB_ * G4_ * 2);   // bf16 packed
    short*    XWc  = (short*)alloc((size_t)2 * TB_ * G4_ * 2);   // bf16 packed
    short*    Y0b  = (short*)alloc((size_t)TB_ * 2 * H_ * 2);    // B out, D out
    short*    Y1b  = (short*)alloc((size_t)TB_ * 2 * H_ * 2);    // C out
    short*    Wpk  = (short*)alloc((size_t)2 * G4_ * H_ * 2);    // per-phase
    short*    Wihb = (short*)alloc((size_t)2 * G4_ * KP_ * 2);   // SA then M0
    short*    WihbL= (short*)alloc((size_t)2 * G4_ * 2 * H_ * 2);// layer at a time
    short*    fc1b = (short*)alloc((size_t)H_ * 2 * H_ * 2);
    short*    xb   = (short*)alloc((size_t)TB_ * KP_ * 2);
    float*    T1b  = (float*)alloc(2 * B_ * H_ * 4);
    float*    Eb   = (float*)alloc(2 * B_ * F_ * 4);
    float*    AB   = (float*)alloc(B_ * F_ * 4);
    float*    saHf = (float*)alloc(2 * B_ * H_ * 4);
    short*    HtA  = (short*)alloc((size_t)2 * 2 * B_ * H_ * 2);
    short*    HtB  = (short*)alloc((size_t)2 * 2 * B_ * H_ * 2);
    short*    HtC  = (short*)alloc((size_t)2 * 2 * B_ * H_ * 2);
    short*    HtD  = (short*)alloc((size_t)2 * 2 * B_ * H_ * 2);
    unsigned* bar  = (unsigned*)alloc(1024);

    if ((size_t)(cur - start) <= ws_size) {
        // =========== overlap path ===========
        auto g16 = [&](const short* Ap, const short* Bp, short* Pp,
                       int K, const float* b1, const float* b2) {
            gemm_bf16<<<dim3(G4_ / 128, TB_ / 128), 256, 0, stream>>>(
                Ap, Bp, nullptr, Pp, TB_, G4_, K, b1, b2);
        };
        auto lstm = [&](const short* XWp, const short* Wp, short* Htp,
                        const float* c0p, short* Yp, int pidx,
                        const short* ja, const short* jb, short* jp, float* jc,
                        const float* b1, const float* b2, int job) {
            lstm_phase<<<dim3(job ? 96 : 32, 2), 256, 0, stream>>>(
                XWp, Wp, Htp, c0p, Yp, bar, pidx, ja, jb, jp, jc, b1, b2, job);
        };

        prep_init<<<256, 256, 0, stream>>>(h0, HtA, HtB, HtC, HtD, bar);
        cv(fc1_W, fc1b, H_ * 2 * H_);
        cv(mL_Wih, WihbL, 2 * G4_ * 2 * H_);             // layer-1 weights
        conv_f2b_pad<<<(2 * G4_ * KP_ + 255) / 256, 256, 0, stream>>>(sa_Wih, Wihb, 2 * G4_, F_, KP_);
        conv_f2b_pad<<<(TB_ * KP_ + 255) / 256, 256, 0, stream>>>(x, xb, TB_, F_, KP_);
        pack_whh<<<(2 * G4_ * H_ + 255) / 256, 256, 0, stream>>>(sa_Whh, Wpk);

        // ---- Phase A (no helpers) ----
        for (int d = 0; d < 2; d++)
            g16(xb, Wihb + (size_t)d * G4_ * KP_, XWa + (size_t)d * TB_ * G4_,
                KP_, sa_bih + d * G4_, sa_bhh + d * G4_);
        lstm(XWa, Wpk, HtA, c0, nullptr, 0,
             nullptr, nullptr, nullptr, nullptr, nullptr, nullptr, 0);
        ht_to_f32<<<256, 256, 0, stream>>>(HtA, saHf);
        gemm_bt<<<dim3(8, 2), 256, 0, stream>>>(saHf, safc1_W, T1b, 2 * B_, H_, H_, safc1_b, 1);
        gemm_bt<<<dim3(2, 2), 256, 0, stream>>>(T1b, safc2_W, Eb, 2 * B_, F_, H_, safc2_b, 2);
        attn_alpha<<<B_, 256, 0, stream>>>(Eb, AB);
        scale_xb<<<(TB_ * KP_ + 255) / 256, 256, 0, stream>>>(x, AB, xb);

        // ---- Phase B (helpers: Y0b x WihbL(l1) -> XWc) ----
        conv_f2b_pad<<<(2 * G4_ * KP_ + 255) / 256, 256, 0, stream>>>(m0_Wih, Wihb, 2 * G4_, F_, KP_);
        for (int d = 0; d < 2; d++)
            g16(xb, Wihb + (size_t)d * G4_ * KP_, XWa + (size_t)d * TB_ * G4_,
                KP_, m0_bih + d * G4_, m0_bhh + d * G4_);
        pack_whh<<<(2 * G4_ * H_ + 255) / 256, 256, 0, stream>>>(m0_Whh, Wpk);
        lstm(XWa, Wpk, HtB, c0, Y0b, 1,
             Y0b, WihbL, XWc, nullptr, mL_bih, mL_bhh, 1);

        // ---- Phase C (helpers: Y1b x WihbL(l2) -> XWa) ----
        cv(mL_Wih + (size_t)2 * G4_ * 2 * H_, WihbL, 2 * G4_ * 2 * H_);  // layer-2
        pack_whh<<<(2 * G4_ * H_ + 255) / 256, 256, 0, stream>>>(mL_Whh, Wpk);
        lstm(XWc, Wpk, HtC, c0 + 2 * B_ * H_, Y1b, 2,
             Y1b, WihbL, XWa, nullptr, mL_bih + 2 * G4_, mL_bhh + 2 * G4_, 1);

        // ---- Phase D (helpers: FC1(Y0b x fc1b) -> d_out) ----
        pack_whh<<<(2 * G4_ * H_ + 255) / 256, 256, 0, stream>>>(mL_Whh + (size_t)2 * G4_ * H_, Wpk);
        lstm(XWa, Wpk, HtD, c0 + 4 * B_ * H_, Y0b, 3,
             Y0b, fc1b, nullptr, (float*)d_out, fc1_b, nullptr, 2);
        return;
    }

    // =========== fallback: R7 serial path (proven; bf16 XW) ===========
    cur = start;
    short*    XW    = (short*)alloc((size_t)2 * TB_ * G4_ * 2);
    float*    T1f   = (float*)alloc(2 * B_ * H_ * 4);
    float*    Ebf   = (float*)alloc(2 * B_ * F_ * 4);
    float*    ABf   = (float*)alloc(B_ * F_ * 4);
    float*    saHff = (float*)alloc(2 * B_ * H_ * 4);
    short*    xbf   = (short*)alloc((size_t)TB_ * KP_ * 2);
    short*    Y0f   = (short*)alloc((size_t)TB_ * 2 * H_ * 2);
    short*    Y1f   = (short*)alloc((size_t)TB_ * 2 * H_ * 2);
    short*    Ht    = (short*)alloc((size_t)2 * 2 * B_ * H_ * 2);
    short*    Wpkf  = (short*)alloc((size_t)2 * G4_ * H_ * 2);
    short*    Wihbf = (short*)alloc((size_t)2 * G4_ * KP_ * 2);
    short*    WihbLf= (short*)alloc((size_t)2 * G4_ * 2 * H_ * 2);
    short*    fc1bf = (short*)alloc((size_t)H_ * 2 * H_ * 2);
    unsigned* barf  = (unsigned*)alloc(1024);

    auto g16f = [&](const short* Ap, const short* Bp, float* Cp, short* Pp,
                    int M, int N, int K, const float* b1, const float* b2) {
        gemm_bf16<<<dim3(N / 128, M / 128), 256, 0, stream>>>(Ap, Bp, Cp, Pp, M, N, K, b1, b2);
    };
    auto phase = [&](const float* Whh_p, const float* h0p, const float* c0p,
                     short* Yout, int pidx) {
        pack_whh<<<(2 * G4_ * H_ + 255) / 256, 256, 0, stream>>>(Whh_p, Wpkf);
        init_phase<<<256, 256, 0, stream>>>(h0p, Ht, barf, pidx == 0 ? 1 : 0);
        lstm_phase<<<dim3(32, 2), 256, 0, stream>>>(XW, Wpkf, Ht, c0p, Yout, barf, pidx,
            nullptr, nullptr, nullptr, nullptr, nullptr, nullptr, 0);
    };

    cv(fc1_W, fc1bf, H_ * 2 * H_);
    conv_f2b_pad<<<(TB_ * KP_ + 255) / 256, 256, 0, stream>>>(x, xbf, TB_, F_, KP_);
    conv_f2b_pad<<<(2 * G4_ * KP_ + 255) / 256, 256, 0, stream>>>(sa_Wih, Wihbf, 2 * G4_, F_, KP_);
    for (int d = 0; d < 2; d++)
        g16f(xbf, Wihbf + (size_t)d * G4_ * KP_, nullptr, XW + (size_t)d * TB_ * G4_,
             TB_, G4_, KP_, sa_bih + d * G4_, sa_bhh + d * G4_);
    phase(sa_Whh, h0, c0, nullptr, 0);
    ht_to_f32<<<256, 256, 0, stream>>>(Ht, saHff);
    gemm_bt<<<dim3(8, 2), 256, 0, stream>>>(saHff, safc1_W, T1f, 2 * B_, H_, H_, safc1_b, 1);
    gemm_bt<<<dim3(2, 2), 256, 0, stream>>>(T1f, safc2_W, Ebf, 2 * B_, F_, H_, safc2_b, 2);
    attn_alpha<<<B_, 256, 0, stream>>>(Ebf, ABf);
    scale_xb<<<(TB_ * KP_ + 255) / 256, 256, 0, stream>>>(x, ABf, xbf);

    conv_f2b_pad<<<(2 * G4_ * KP_ + 255) / 256, 256, 0, stream>>>(m0_Wih, Wihbf, 2 * G4_, F_, KP_);
    for (int d = 0; d < 2; d++)
        g16f(xbf, Wihbf + (size_t)d * G4_ * KP_, nullptr, XW + (size_t)d * TB_ * G4_,
             TB_, G4_, KP_, m0_bih + d * G4_, m0_bhh + d * G4_);
    phase(m0_Whh, h0, c0, Y0f, 1);

    cv(mL_Wih, WihbLf, 2 * G4_ * 2 * H_);
    for (int d = 0; d < 2; d++)
        g16f(Y0f, WihbLf + (size_t)d * G4_ * 2 * H_, nullptr, XW + (size_t)d * TB_ * G4_,
             TB_, G4_, 2 * H_, mL_bih + d * G4_, mL_bhh + d * G4_);
    phase(mL_Whh, h0 + 2 * B_ * H_, c0 + 2 * B_ * H_, Y1f, 2);

    cv(mL_Wih + (size_t)2 * G4_ * 2 * H_, WihbLf, 2 * G4_ * 2 * H_);
    for (int d = 0; d < 2; d++)
        g16f(Y1f, WihbLf + (size_t)d * G4_ * 2 * H_, nullptr, XW + (size_t)d * TB_ * G4_,
             TB_, G4_, 2 * H_, mL_bih + (2 + d) * G4_, mL_bhh + (2 + d) * G4_);
    phase(mL_Whh + (size_t)2 * G4_ * H_, h0 + 4 * B_ * H_, c0 + 4 * B_ * H_, Y0f, 3);

    g16f(Y0f, fc1bf, (float*)d_out, nullptr, TB_, H_, 2 * H_, fc1_b, nullptr);
}